// Round 13
// baseline (171.386 us; speedup 1.0000x reference)
//
#include <hip/hip_runtime.h>
#include <hip/hip_fp16.h>

// GCNConv (self-loops, symmetric norm) + bias + PReLU, fp32, N=100k, D=64, E=1.6M.
//
// Padded-bucket front end + src-tiled gather for L2 locality:
//   1. k_detect: edge_index storage (int64 vs int32); init bucket cursors
//   2. k_scat:   single edge pass; LDS count -> one global atomicAdd per bucket
//                -> LDS-rank write of (dst&127)<<17|src into padded part[]
//   3. k_p2:     per-bucket: LDS count per (dst, src-tile) -> csr sorted by
//                (dst, tile); emits base[dst], packed per-tile byte counts,
//                dinv[dst]
//   4. k_gemm:   xwsh = fp16((x @ W) * dinv[row])   (LDS-tiled, 128 rows/block)
//   5. k_gather: 4 dsts per 16-lane group; tile-ordered outer loop so all
//                waves touch the same 1MB slice of xwsh concurrently (L2-hot)

static inline int iceil(long long a, int b) { return (int)((a + (long long)b - 1) / b); }

#define NSCAT 512         // scatter blocks
#define CAP 4096          // padded slots per 128-dst bucket (mean fill ~2046)
#define NBUK_MAX 1024     // supports N <= 131072
#define TSH 13            // src-tile shift: 8192 rows = 1MB of fp16 table
#define MAXT 16           // max tiles (N <= 131072)

__global__ void k_detect(const int* __restrict__ ei, long long n_i32_min,
                         int* __restrict__ flag, int* __restrict__ gcur, int nbuk) {
    __shared__ int nz;
    if (threadIdx.x == 0) nz = 0;
    __syncthreads();
    long long half = n_i32_min >> 1;
    long long step = half / 4096;
    if (step == 0) step = 1;
    for (int t = threadIdx.x; t < 4096; t += blockDim.x) {
        long long k = (long long)t * step;
        if (k < half && ei[2 * k + 1] != 0) nz = 1;  // benign race
    }
    for (int b = threadIdx.x; b < nbuk; b += blockDim.x) gcur[b] = b * CAP;
    __syncthreads();
    if (threadIdx.x == 0) *flag = nz ? 1 : 2;
}

// single-pass scatter: count chunk in LDS, reserve via one global atomic per
// nonempty bucket, re-walk chunk (L2-hot) writing ranked entries.
__global__ __launch_bounds__(256) void k_scat(const int* __restrict__ ei,
                                              const int* __restrict__ flag,
                                              int* __restrict__ gcur,
                                              int* __restrict__ part,
                                              long long E, int nbuk, int chunk) {
    __shared__ int hist[NBUK_MAX];
    __shared__ int sbase[NBUK_MAX];
    for (int i = threadIdx.x; i < nbuk; i += 256) hist[i] = 0;
    __syncthreads();
    const int st = *flag;
    long long beg = (long long)blockIdx.x * chunk;
    long long end = beg + chunk; if (end > E) end = E;
    for (long long e = beg + threadIdx.x; e < end; e += 256) {
        int d = ei[(E + e) * st];
        atomicAdd(&hist[d >> 7], 1);
    }
    __syncthreads();
    for (int i = threadIdx.x; i < nbuk; i += 256) {
        int c = hist[i];
        sbase[i] = c ? atomicAdd(&gcur[i], c) : 0;
        hist[i] = 0;  // reuse as rank counter
    }
    __syncthreads();
    for (long long e = beg + threadIdx.x; e < end; e += 256) {
        int s = ei[e * st];
        int d = ei[(E + e) * st];
        int b = d >> 7;
        int r = atomicAdd(&hist[b], 1);
        part[sbase[b] + r] = ((d & 127) << 17) | s;   // s < 2^17
    }
}

// per-bucket: count per (dst, src-tile), emit csr ordered by (dst, tile) plus
// base[dst], packed byte counts (uint4), dinv[dst].
__global__ __launch_bounds__(256) void k_p2(const int* __restrict__ part,
                                            const int* __restrict__ gcur,
                                            int* __restrict__ basea,
                                            uint4* __restrict__ cntsa,
                                            float* __restrict__ dinv,
                                            int* __restrict__ csr, int N) {
    __shared__ int cnt2[128][MAXT];  // counts per (dl, tile)
    __shared__ int rnk2[128][MAXT];  // absolute running positions
    __shared__ int cnt[128], inc[128], exc[128];
    const int b = blockIdx.x, t = threadIdx.x;
    const int beg = b * CAP, end = gcur[b];
    for (int i = t; i < 128 * MAXT; i += 256) ((int*)cnt2)[i] = 0;
    __syncthreads();
    for (int i = beg + t; i < end; i += 256) {
        int v = part[i];
        atomicAdd(&cnt2[(v >> 17) & 127][(v & 0x1FFFF) >> TSH], 1);
    }
    __syncthreads();
    if (t < 128) {
        int run = 0;
#pragma unroll
        for (int tt = 0; tt < MAXT; ++tt) { rnk2[t][tt] = run; run += cnt2[t][tt]; }
        cnt[t] = run;
        inc[t] = run;
    }
    __syncthreads();
    for (int off = 1; off < 128; off <<= 1) {
        int v = (t < 128 && t >= off) ? inc[t - off] : 0;
        __syncthreads();
        if (t < 128) inc[t] += v;
        __syncthreads();
    }
    if (t < 128) {
        exc[t] = inc[t] - cnt[t];
        int dst = b * 128 + t;
        int ab = beg + exc[t];
#pragma unroll
        for (int tt = 0; tt < MAXT; ++tt) rnk2[t][tt] += ab;
        if (dst < N) {
            basea[dst] = ab;
            dinv[dst] = rsqrtf((float)cnt[t] + 1.0f);  // +1 self loop
            uint4 pc;
            pc.x = (cnt2[t][0])       | (cnt2[t][1] << 8) |
                   (cnt2[t][2] << 16) | (cnt2[t][3] << 24);
            pc.y = (cnt2[t][4])       | (cnt2[t][5] << 8) |
                   (cnt2[t][6] << 16) | (cnt2[t][7] << 24);
            pc.z = (cnt2[t][8])       | (cnt2[t][9] << 8) |
                   (cnt2[t][10] << 16)| (cnt2[t][11] << 24);
            pc.w = (cnt2[t][12])      | (cnt2[t][13] << 8) |
                   (cnt2[t][14] << 16)| (cnt2[t][15] << 24);
            cntsa[dst] = pc;
        }
    }
    __syncthreads();
    for (int i = beg + t; i < end; i += 256) {
        int v = part[i];
        int s = v & 0x1FFFF;
        int pos = atomicAdd(&rnk2[(v >> 17) & 127][s >> TSH], 1);
        csr[pos] = s;
    }
}

// xwsh = fp16((x @ W) * dinv[row]).  LDS-tiled, coalesced loads, 8x4 per thread.
__global__ __launch_bounds__(256) void k_gemm(const float* __restrict__ x,
                                              const float* __restrict__ W,
                                              const float* __restrict__ dinv,
                                              __half* __restrict__ xwsh, int N) {
    __shared__ float Ws[64 * 64];
    __shared__ float xT[64][132];
    const int tid = threadIdx.x;
    {
        const float4* W4 = (const float4*)W;
        float4* Ws4 = (float4*)Ws;
#pragma unroll
        for (int j = 0; j < 4; ++j) Ws4[tid + 256 * j] = W4[tid + 256 * j];
    }
    const int tile0 = blockIdx.x * 128;
    {
        const int lr = tid >> 4;
        const int c4 = (tid & 15) * 4;
#pragma unroll
        for (int i = 0; i < 8; ++i) {
            int row = lr + 16 * i;
            int gr = tile0 + row;
            if (gr >= N) gr = N - 1;
            float4 v = *(const float4*)(x + (long long)gr * 64 + c4);
            xT[c4 + 0][row] = v.x;
            xT[c4 + 1][row] = v.y;
            xT[c4 + 2][row] = v.z;
            xT[c4 + 3][row] = v.w;
        }
    }
    __syncthreads();
    const int ri = tid >> 4;
    const int ci = tid & 15;
    float acc[8][4];
#pragma unroll
    for (int j = 0; j < 8; ++j)
#pragma unroll
        for (int c = 0; c < 4; ++c) acc[j][c] = 0.0f;
#pragma unroll 4
    for (int k = 0; k < 64; ++k) {
        float4 xa = *(const float4*)&xT[k][8 * ri];
        float4 xb = *(const float4*)&xT[k][8 * ri + 4];
        float4 wv = *(const float4*)&Ws[k * 64 + 4 * ci];
        float xr[8] = {xa.x, xa.y, xa.z, xa.w, xb.x, xb.y, xb.z, xb.w};
        float wc[4] = {wv.x, wv.y, wv.z, wv.w};
#pragma unroll
        for (int j = 0; j < 8; ++j)
#pragma unroll
            for (int c = 0; c < 4; ++c) acc[j][c] = fmaf(xr[j], wc[c], acc[j][c]);
    }
#pragma unroll
    for (int j = 0; j < 8; ++j) {
        int gr = tile0 + 8 * ri + j;
        if (gr < N) {
            float di = dinv[gr];
            __half2 h01 = __floats2half2_rn(acc[j][0] * di, acc[j][1] * di);
            __half2 h23 = __floats2half2_rn(acc[j][2] * di, acc[j][3] * di);
            uint2 u;
            u.x = *(unsigned int*)&h01;
            u.y = *(unsigned int*)&h23;
            *(uint2*)(xwsh + (long long)gr * 64 + 4 * ci) = u;  // 8B store
        }
    }
}

// tile-ordered gather: 16-lane group owns 4 consecutive dsts (full 64-feature
// rows, 4 features/lane). Outer loop over src tiles keeps all waves in the
// same 1MB slice of xwsh. Per tile: lockstep predicated edge walk over the 4
// dsts (4 independent row loads in flight per group, 16 per wave).
__global__ __launch_bounds__(256) void k_gather(const int* __restrict__ csr,
                                                const int* __restrict__ basea,
                                                const uint4* __restrict__ cntsa,
                                                const float* __restrict__ dinv,
                                                const __half* __restrict__ xwsh,
                                                const float* __restrict__ b,
                                                const float* __restrict__ pa,
                                                float* __restrict__ out,
                                                int N, int ntile) {
    const int lane = threadIdx.x & 63;
    const int g = lane >> 4;
    const int fl = lane & 15;
    const int wib = threadIdx.x >> 6;
    const int gg = (blockIdx.x * 4 + wib) * 4 + g;  // global 16-lane group id
    const int d0 = gg * 4;
    const float slope = pa[0];
    const float4 b4 = ((const float4*)b)[fl];

    const bool v0 = d0 < N, v1 = d0 + 1 < N, v2 = d0 + 2 < N, v3 = d0 + 3 < N;
    int cur0 = v0 ? basea[d0] : 0;
    int cur1 = v1 ? basea[d0 + 1] : 0;
    int cur2 = v2 ? basea[d0 + 2] : 0;
    int cur3 = v3 ? basea[d0 + 3] : 0;
    const uint4 z = make_uint4(0, 0, 0, 0);
    const uint4 c0 = v0 ? cntsa[d0] : z;
    const uint4 c1 = v1 ? cntsa[d0 + 1] : z;
    const uint4 c2 = v2 ? cntsa[d0 + 2] : z;
    const uint4 c3 = v3 ? cntsa[d0 + 3] : z;

    float4 a0 = {0, 0, 0, 0}, a1 = {0, 0, 0, 0}, a2 = {0, 0, 0, 0}, a3 = {0, 0, 0, 0};

#define CW(c, tt) ((tt) < 4 ? (c).x : ((tt) < 8 ? (c).y : ((tt) < 12 ? (c).z : (c).w)))
#define EDGE(P, CUR, A)                                                       \
    if (P) {                                                                  \
        int s = csr[(CUR) + k];                                               \
        uint2 u = *(const uint2*)(xwsh + (long long)s * 64 + 4 * fl);         \
        float2 f01 = __half22float2(*(const __half2*)&u.x);                   \
        float2 f23 = __half22float2(*(const __half2*)&u.y);                   \
        A.x += f01.x; A.y += f01.y; A.z += f23.x; A.w += f23.y;               \
    }

#pragma unroll
    for (int tt = 0; tt < MAXT; ++tt) {
        if (tt >= ntile) break;
        const int sh = (tt & 3) * 8;
        int n0 = (CW(c0, tt) >> sh) & 255;
        int n1 = (CW(c1, tt) >> sh) & 255;
        int n2 = (CW(c2, tt) >> sh) & 255;
        int n3 = (CW(c3, tt) >> sh) & 255;
        for (int k = 0;; ++k) {
            bool p0 = k < n0, p1 = k < n1, p2 = k < n2, p3 = k < n3;
            if (!__any(p0 | p1 | p2 | p3)) break;
            EDGE(p0, cur0, a0)
            EDGE(p1, cur1, a1)
            EDGE(p2, cur2, a2)
            EDGE(p3, cur3, a3)
        }
        cur0 += n0; cur1 += n1; cur2 += n2; cur3 += n3;
    }
#undef EDGE
#undef CW

#define EPI(P, DI, A)                                                         \
    if (P) {                                                                  \
        int d = (DI);                                                         \
        uint2 u = *(const uint2*)(xwsh + (long long)d * 64 + 4 * fl);         \
        float2 s01 = __half22float2(*(const __half2*)&u.x);                   \
        float2 s23 = __half22float2(*(const __half2*)&u.y);                   \
        float di = dinv[d];                                                   \
        float4 v;                                                             \
        v.x = di * (A.x + s01.x) + b4.x;                                      \
        v.y = di * (A.y + s01.y) + b4.y;                                      \
        v.z = di * (A.z + s23.x) + b4.z;                                      \
        v.w = di * (A.w + s23.y) + b4.w;                                      \
        v.x = v.x >= 0.f ? v.x : slope * v.x;                                 \
        v.y = v.y >= 0.f ? v.y : slope * v.y;                                 \
        v.z = v.z >= 0.f ? v.z : slope * v.z;                                 \
        v.w = v.w >= 0.f ? v.w : slope * v.w;                                 \
        *(float4*)(out + (long long)d * 64 + 4 * fl) = v;                     \
    }
    EPI(v0, d0, a0)
    EPI(v1, d0 + 1, a1)
    EPI(v2, d0 + 2, a2)
    EPI(v3, d0 + 3, a3)
#undef EPI
}

extern "C" void kernel_launch(void* const* d_in, const int* in_sizes, int n_in,
                              void* d_out, int out_size, void* d_ws, size_t ws_size,
                              hipStream_t stream) {
    const float* x  = (const float*)d_in[0];
    const int*   ei = (const int*)d_in[1];
    const float* W  = (const float*)d_in[2];
    const float* b  = (const float*)d_in[3];
    const float* pa = (const float*)d_in[4];
    float* out = (float*)d_out;

    const int N = in_sizes[0] / 64;
    const long long E = (long long)in_sizes[1] / 2;
    const int nbuk = (N + 127) >> 7;               // 782 for N=100k
    const int chunk = iceil(E, NSCAT);
    const int ntile = (N + (1 << TSH) - 1) >> TSH; // 13 for N=100k (<= MAXT)

    char* ws = (char*)d_ws;
    size_t o = 0;
    int*    flag  = (int*)(ws + o);   o += 256;
    int*    gcur  = (int*)(ws + o);   o += ((size_t)nbuk * 4 + 255) & ~(size_t)255;
    int*    basea = (int*)(ws + o);   o += ((size_t)N * 4 + 255) & ~(size_t)255;
    uint4*  cntsa = (uint4*)(ws + o); o += ((size_t)N * 16 + 255) & ~(size_t)255;
    float*  dinv  = (float*)(ws + o); o += ((size_t)N * 4 + 255) & ~(size_t)255;
    int*    part  = (int*)(ws + o);   o += ((size_t)nbuk * CAP * 4 + 255) & ~(size_t)255;
    int*    csr   = (int*)(ws + o);   o += ((size_t)nbuk * CAP * 4 + 255) & ~(size_t)255;
    __half* xwsh  = (__half*)(ws + o);  // N*64*2 = 12.8 MB; total ~42 MB

    k_detect<<<1, 256, 0, stream>>>(ei, (long long)in_sizes[1], flag, gcur, nbuk);
    k_scat<<<NSCAT, 256, 0, stream>>>(ei, flag, gcur, part, E, nbuk, chunk);
    k_p2<<<nbuk, 256, 0, stream>>>(part, gcur, basea, cntsa, dinv, csr, N);
    k_gemm<<<iceil(N, 128), 256, 0, stream>>>(x, W, dinv, xwsh, N);
    k_gather<<<2048, 256, 0, stream>>>(csr, basea, cntsa, dinv, xwsh, b, pa, out,
                                       N, ntile);
}

// Round 14
// 161.835 us; speedup vs baseline: 1.0590x; 1.0590x over previous
//
#include <hip/hip_runtime.h>
#include <hip/hip_fp16.h>

// GCNConv (self-loops, symmetric norm) + bias + PReLU, fp32, N=100k, D=64, E=1.6M.
//
// Padded-bucket front end + tile-sorted CSR + phase-synced gather:
//   1. k_detect: edge_index storage (int64 vs int32); init bucket cursors
//   2. k_scat:   single edge pass; LDS count -> one global atomicAdd per bucket
//                -> LDS-rank write of (dst&127)<<17|src into padded part[]
//   3. k_p2:     per-bucket: LDS count per (dst, src-tile) -> csr sorted by
//                (dst, tile); emits base[dst], packed per-tile counts, dinv
//   4. k_gemm:   xwsh = fp16((x @ W) * dinv[row])   (LDS-tiled, 128 rows/block)
//   5. k_gather: one dst per 16-lane group (4 features/lane); flat branchless
//                per-tile walk; strided dst assignment keeps all groups in the
//                same src tile concurrently (L2-hot 1MB slices)

static inline int iceil(long long a, int b) { return (int)((a + (long long)b - 1) / b); }

#define NSCAT 512         // scatter blocks
#define CAP 4096          // padded slots per 128-dst bucket (mean fill ~2046)
#define NBUK_MAX 1024     // supports N <= 131072
#define TSH 13            // src-tile shift: 8192 rows = 1MB of fp16 table
#define MAXT 16           // max tiles (N <= 131072)

__global__ void k_detect(const int* __restrict__ ei, long long n_i32_min,
                         int* __restrict__ flag, int* __restrict__ gcur, int nbuk) {
    __shared__ int nz;
    if (threadIdx.x == 0) nz = 0;
    __syncthreads();
    long long half = n_i32_min >> 1;
    long long step = half / 4096;
    if (step == 0) step = 1;
    for (int t = threadIdx.x; t < 4096; t += blockDim.x) {
        long long k = (long long)t * step;
        if (k < half && ei[2 * k + 1] != 0) nz = 1;  // benign race
    }
    for (int b = threadIdx.x; b < nbuk; b += blockDim.x) gcur[b] = b * CAP;
    __syncthreads();
    if (threadIdx.x == 0) *flag = nz ? 1 : 2;
}

// single-pass scatter: count chunk in LDS, reserve via one global atomic per
// nonempty bucket, re-walk chunk (L2-hot) writing ranked entries.
__global__ __launch_bounds__(256) void k_scat(const int* __restrict__ ei,
                                              const int* __restrict__ flag,
                                              int* __restrict__ gcur,
                                              int* __restrict__ part,
                                              long long E, int nbuk, int chunk) {
    __shared__ int hist[NBUK_MAX];
    __shared__ int sbase[NBUK_MAX];
    for (int i = threadIdx.x; i < nbuk; i += 256) hist[i] = 0;
    __syncthreads();
    const int st = *flag;
    long long beg = (long long)blockIdx.x * chunk;
    long long end = beg + chunk; if (end > E) end = E;
    for (long long e = beg + threadIdx.x; e < end; e += 256) {
        int d = ei[(E + e) * st];
        atomicAdd(&hist[d >> 7], 1);
    }
    __syncthreads();
    for (int i = threadIdx.x; i < nbuk; i += 256) {
        int c = hist[i];
        sbase[i] = c ? atomicAdd(&gcur[i], c) : 0;
        hist[i] = 0;  // reuse as rank counter
    }
    __syncthreads();
    for (long long e = beg + threadIdx.x; e < end; e += 256) {
        int s = ei[e * st];
        int d = ei[(E + e) * st];
        int b = d >> 7;
        int r = atomicAdd(&hist[b], 1);
        part[sbase[b] + r] = ((d & 127) << 17) | s;   // s < 2^17
    }
}

// per-bucket: count per (dst, src-tile), emit csr ordered by (dst, tile) plus
// base[dst], packed byte counts (uint4), dinv[dst].
__global__ __launch_bounds__(256) void k_p2(const int* __restrict__ part,
                                            const int* __restrict__ gcur,
                                            int* __restrict__ basea,
                                            uint4* __restrict__ cntsa,
                                            float* __restrict__ dinv,
                                            int* __restrict__ csr, int N) {
    __shared__ int cnt2[128][MAXT];  // counts per (dl, tile)
    __shared__ int rnk2[128][MAXT];  // absolute running positions
    __shared__ int cnt[128], inc[128], exc[128];
    const int b = blockIdx.x, t = threadIdx.x;
    const int beg = b * CAP, end = gcur[b];
    for (int i = t; i < 128 * MAXT; i += 256) ((int*)cnt2)[i] = 0;
    __syncthreads();
    for (int i = beg + t; i < end; i += 256) {
        int v = part[i];
        atomicAdd(&cnt2[(v >> 17) & 127][(v & 0x1FFFF) >> TSH], 1);
    }
    __syncthreads();
    if (t < 128) {
        int run = 0;
#pragma unroll
        for (int tt = 0; tt < MAXT; ++tt) { rnk2[t][tt] = run; run += cnt2[t][tt]; }
        cnt[t] = run;
        inc[t] = run;
    }
    __syncthreads();
    for (int off = 1; off < 128; off <<= 1) {
        int v = (t < 128 && t >= off) ? inc[t - off] : 0;
        __syncthreads();
        if (t < 128) inc[t] += v;
        __syncthreads();
    }
    if (t < 128) {
        exc[t] = inc[t] - cnt[t];
        int dst = b * 128 + t;
        int ab = beg + exc[t];
#pragma unroll
        for (int tt = 0; tt < MAXT; ++tt) rnk2[t][tt] += ab;
        if (dst < N) {
            basea[dst] = ab;
            dinv[dst] = rsqrtf((float)cnt[t] + 1.0f);  // +1 self loop
            uint4 pc;
            pc.x = (cnt2[t][0])       | (cnt2[t][1] << 8) |
                   (cnt2[t][2] << 16) | (cnt2[t][3] << 24);
            pc.y = (cnt2[t][4])       | (cnt2[t][5] << 8) |
                   (cnt2[t][6] << 16) | (cnt2[t][7] << 24);
            pc.z = (cnt2[t][8])       | (cnt2[t][9] << 8) |
                   (cnt2[t][10] << 16)| (cnt2[t][11] << 24);
            pc.w = (cnt2[t][12])      | (cnt2[t][13] << 8) |
                   (cnt2[t][14] << 16)| (cnt2[t][15] << 24);
            cntsa[dst] = pc;
        }
    }
    __syncthreads();
    for (int i = beg + t; i < end; i += 256) {
        int v = part[i];
        int s = v & 0x1FFFF;
        int pos = atomicAdd(&rnk2[(v >> 17) & 127][s >> TSH], 1);
        csr[pos] = s;
    }
}

// xwsh = fp16((x @ W) * dinv[row]).  LDS-tiled, coalesced loads, 8x4 per thread.
__global__ __launch_bounds__(256) void k_gemm(const float* __restrict__ x,
                                              const float* __restrict__ W,
                                              const float* __restrict__ dinv,
                                              __half* __restrict__ xwsh, int N) {
    __shared__ float Ws[64 * 64];
    __shared__ float xT[64][132];
    const int tid = threadIdx.x;
    {
        const float4* W4 = (const float4*)W;
        float4* Ws4 = (float4*)Ws;
#pragma unroll
        for (int j = 0; j < 4; ++j) Ws4[tid + 256 * j] = W4[tid + 256 * j];
    }
    const int tile0 = blockIdx.x * 128;
    {
        const int lr = tid >> 4;
        const int c4 = (tid & 15) * 4;
#pragma unroll
        for (int i = 0; i < 8; ++i) {
            int row = lr + 16 * i;
            int gr = tile0 + row;
            if (gr >= N) gr = N - 1;
            float4 v = *(const float4*)(x + (long long)gr * 64 + c4);
            xT[c4 + 0][row] = v.x;
            xT[c4 + 1][row] = v.y;
            xT[c4 + 2][row] = v.z;
            xT[c4 + 3][row] = v.w;
        }
    }
    __syncthreads();
    const int ri = tid >> 4;
    const int ci = tid & 15;
    float acc[8][4];
#pragma unroll
    for (int j = 0; j < 8; ++j)
#pragma unroll
        for (int c = 0; c < 4; ++c) acc[j][c] = 0.0f;
#pragma unroll 4
    for (int k = 0; k < 64; ++k) {
        float4 xa = *(const float4*)&xT[k][8 * ri];
        float4 xb = *(const float4*)&xT[k][8 * ri + 4];
        float4 wv = *(const float4*)&Ws[k * 64 + 4 * ci];
        float xr[8] = {xa.x, xa.y, xa.z, xa.w, xb.x, xb.y, xb.z, xb.w};
        float wc[4] = {wv.x, wv.y, wv.z, wv.w};
#pragma unroll
        for (int j = 0; j < 8; ++j)
#pragma unroll
            for (int c = 0; c < 4; ++c) acc[j][c] = fmaf(xr[j], wc[c], acc[j][c]);
    }
#pragma unroll
    for (int j = 0; j < 8; ++j) {
        int gr = tile0 + 8 * ri + j;
        if (gr < N) {
            float di = dinv[gr];
            __half2 h01 = __floats2half2_rn(acc[j][0] * di, acc[j][1] * di);
            __half2 h23 = __floats2half2_rn(acc[j][2] * di, acc[j][3] * di);
            uint2 u;
            u.x = *(unsigned int*)&h01;
            u.y = *(unsigned int*)&h23;
            *(uint2*)(xwsh + (long long)gr * 64 + 4 * ci) = u;  // 8B store
        }
    }
}

// phase-synced gather: 16-lane group owns one dst (4 features/lane, full 128B
// row per group). Flat branchless walk of the dst's tile-sorted edges; strided
// dst assignment keeps all 32768 groups in the same src tile window.
__global__ __launch_bounds__(256) void k_gather(const int* __restrict__ csr,
                                                const int* __restrict__ basea,
                                                const uint4* __restrict__ cntsa,
                                                const float* __restrict__ dinv,
                                                const __half* __restrict__ xwsh,
                                                const float* __restrict__ b,
                                                const float* __restrict__ pa,
                                                float* __restrict__ out,
                                                int N, int ntile) {
    const int lane = threadIdx.x & 63;
    const int g = lane >> 4;
    const int fl = lane & 15;
    const int wib = threadIdx.x >> 6;
    const int group = (blockIdx.x * 4 + wib) * 4 + g;   // global 16-lane group
    const int ngroups = gridDim.x * 16;
    const float slope = pa[0];
    const float4 b4 = ((const float4*)b)[fl];

    for (int d = group; d < N; d += ngroups) {   // strided: global tile phase
        int cur = basea[d];
        const uint4 c = cntsa[d];
        float ax = 0.f, ay = 0.f, az = 0.f, aw = 0.f;
        for (int tt = 0; tt < ntile; ++tt) {
            unsigned w = tt < 4 ? c.x : tt < 8 ? c.y : tt < 12 ? c.z : c.w;
            int n = (w >> ((tt & 3) * 8)) & 255;
            for (int k = 0; k < n; ++k) {
                int s = csr[cur + k];            // 16-lane broadcast load
                uint2 u = *(const uint2*)(xwsh + (long long)s * 64 + 4 * fl);
                float2 f01 = __half22float2(*(const __half2*)&u.x);
                float2 f23 = __half22float2(*(const __half2*)&u.y);
                ax += f01.x; ay += f01.y; az += f23.x; aw += f23.y;
            }
            cur += n;
        }
        uint2 u = *(const uint2*)(xwsh + (long long)d * 64 + 4 * fl);  // self
        float2 s01 = __half22float2(*(const __half2*)&u.x);
        float2 s23 = __half22float2(*(const __half2*)&u.y);
        float di = dinv[d];
        float4 v;
        v.x = di * (ax + s01.x) + b4.x;
        v.y = di * (ay + s01.y) + b4.y;
        v.z = di * (az + s23.x) + b4.z;
        v.w = di * (aw + s23.y) + b4.w;
        v.x = v.x >= 0.f ? v.x : slope * v.x;
        v.y = v.y >= 0.f ? v.y : slope * v.y;
        v.z = v.z >= 0.f ? v.z : slope * v.z;
        v.w = v.w >= 0.f ? v.w : slope * v.w;
        *(float4*)(out + (long long)d * 64 + 4 * fl) = v;
    }
}

extern "C" void kernel_launch(void* const* d_in, const int* in_sizes, int n_in,
                              void* d_out, int out_size, void* d_ws, size_t ws_size,
                              hipStream_t stream) {
    const float* x  = (const float*)d_in[0];
    const int*   ei = (const int*)d_in[1];
    const float* W  = (const float*)d_in[2];
    const float* b  = (const float*)d_in[3];
    const float* pa = (const float*)d_in[4];
    float* out = (float*)d_out;

    const int N = in_sizes[0] / 64;
    const long long E = (long long)in_sizes[1] / 2;
    const int nbuk = (N + 127) >> 7;               // 782 for N=100k
    const int chunk = iceil(E, NSCAT);
    const int ntile = (N + (1 << TSH) - 1) >> TSH; // 13 for N=100k (<= MAXT)

    char* ws = (char*)d_ws;
    size_t o = 0;
    int*    flag  = (int*)(ws + o);   o += 256;
    int*    gcur  = (int*)(ws + o);   o += ((size_t)nbuk * 4 + 255) & ~(size_t)255;
    int*    basea = (int*)(ws + o);   o += ((size_t)N * 4 + 255) & ~(size_t)255;
    uint4*  cntsa = (uint4*)(ws + o); o += ((size_t)N * 16 + 255) & ~(size_t)255;
    float*  dinv  = (float*)(ws + o); o += ((size_t)N * 4 + 255) & ~(size_t)255;
    int*    part  = (int*)(ws + o);   o += ((size_t)nbuk * CAP * 4 + 255) & ~(size_t)255;
    int*    csr   = (int*)(ws + o);   o += ((size_t)nbuk * CAP * 4 + 255) & ~(size_t)255;
    __half* xwsh  = (__half*)(ws + o);  // N*64*2 = 12.8 MB; total ~42 MB

    k_detect<<<1, 256, 0, stream>>>(ei, (long long)in_sizes[1], flag, gcur, nbuk);
    k_scat<<<NSCAT, 256, 0, stream>>>(ei, flag, gcur, part, E, nbuk, chunk);
    k_p2<<<nbuk, 256, 0, stream>>>(part, gcur, basea, cntsa, dinv, csr, N);
    k_gemm<<<iceil(N, 128), 256, 0, stream>>>(x, W, dinv, xwsh, N);
    k_gather<<<2048, 256, 0, stream>>>(csr, basea, cntsa, dinv, xwsh, b, pa, out,
                                       N, ntile);
}

// Round 15
// 102.974 us; speedup vs baseline: 1.6644x; 1.5716x over previous
//
#include <hip/hip_runtime.h>
#include <hip/hip_fp16.h>

// GCNConv (self-loops, symmetric norm) + bias + PReLU, fp32, N=100k, D=64, E=1.6M.
//
// Padded-bucket front end + fused (LDS-CSR build + gather):
//   1. k_detect: edge_index storage (int64 vs int32); init bucket cursors
//   2. k_scat:   single edge pass; LDS count -> one global atomicAdd per bucket
//                -> LDS-rank write of (dst&127)<<17|src into padded part[]
//   3. k_cnt:    per-bucket LDS count of 128 dsts -> dinv  (gemm needs it)
//   4. k_gemm:   xwsh = fp16((x @ W) * dinv[row])   (LDS-tiled, 128 rows/block)
//   5. k_gfuse:  per-bucket: count -> scan -> rank-place csr in LDS (16KB),
//                then R12-style 4-deep unrolled gather from LDS indices;
//                fused self-loop + bias + PReLU epilogue.

static inline int iceil(long long a, int b) { return (int)((a + (long long)b - 1) / b); }

#define NSCAT 512         // scatter blocks
#define CAP 4096          // padded slots per 128-dst bucket (mean fill ~2046)
#define NBUK_MAX 1024     // supports N <= 131072

__global__ void k_detect(const int* __restrict__ ei, long long n_i32_min,
                         int* __restrict__ flag, int* __restrict__ gcur, int nbuk) {
    __shared__ int nz;
    if (threadIdx.x == 0) nz = 0;
    __syncthreads();
    long long half = n_i32_min >> 1;
    long long step = half / 4096;
    if (step == 0) step = 1;
    for (int t = threadIdx.x; t < 4096; t += blockDim.x) {
        long long k = (long long)t * step;
        if (k < half && ei[2 * k + 1] != 0) nz = 1;  // benign race
    }
    for (int b = threadIdx.x; b < nbuk; b += blockDim.x) gcur[b] = b * CAP;
    __syncthreads();
    if (threadIdx.x == 0) *flag = nz ? 1 : 2;
}

// single-pass scatter: count chunk in LDS, reserve via one global atomic per
// nonempty bucket, re-walk chunk (L2-hot) writing ranked entries.
__global__ __launch_bounds__(256) void k_scat(const int* __restrict__ ei,
                                              const int* __restrict__ flag,
                                              int* __restrict__ gcur,
                                              int* __restrict__ part,
                                              long long E, int nbuk, int chunk) {
    __shared__ int hist[NBUK_MAX];
    __shared__ int sbase[NBUK_MAX];
    for (int i = threadIdx.x; i < nbuk; i += 256) hist[i] = 0;
    __syncthreads();
    const int st = *flag;
    long long beg = (long long)blockIdx.x * chunk;
    long long end = beg + chunk; if (end > E) end = E;
    for (long long e = beg + threadIdx.x; e < end; e += 256) {
        int d = ei[(E + e) * st];
        atomicAdd(&hist[d >> 7], 1);
    }
    __syncthreads();
    for (int i = threadIdx.x; i < nbuk; i += 256) {
        int c = hist[i];
        sbase[i] = c ? atomicAdd(&gcur[i], c) : 0;
        hist[i] = 0;  // reuse as rank counter
    }
    __syncthreads();
    for (long long e = beg + threadIdx.x; e < end; e += 256) {
        int s = ei[e * st];
        int d = ei[(E + e) * st];
        int b = d >> 7;
        int r = atomicAdd(&hist[b], 1);
        part[sbase[b] + r] = ((d & 127) << 17) | s;   // s < 2^17
    }
}

// per-bucket count of 128 dsts -> dinv (consumed by gemm)
__global__ __launch_bounds__(256) void k_cnt(const int* __restrict__ part,
                                             const int* __restrict__ gcur,
                                             float* __restrict__ dinv, int N) {
    __shared__ int cnt[128];
    const int t = threadIdx.x;
    if (t < 128) cnt[t] = 0;
    __syncthreads();
    const int beg = blockIdx.x * CAP, end = gcur[blockIdx.x];
    for (int i = beg + t; i < end; i += 256)
        atomicAdd(&cnt[(part[i] >> 17) & 127], 1);
    __syncthreads();
    if (t < 128) {
        int d = blockIdx.x * 128 + t;
        if (d < N) dinv[d] = rsqrtf((float)cnt[t] + 1.0f);  // +1 self loop
    }
}

// xwsh = fp16((x @ W) * dinv[row]).  LDS-tiled, coalesced loads, 8x4 per thread.
__global__ __launch_bounds__(256) void k_gemm(const float* __restrict__ x,
                                              const float* __restrict__ W,
                                              const float* __restrict__ dinv,
                                              __half* __restrict__ xwsh, int N) {
    __shared__ float Ws[64 * 64];
    __shared__ float xT[64][132];
    const int tid = threadIdx.x;
    {
        const float4* W4 = (const float4*)W;
        float4* Ws4 = (float4*)Ws;
#pragma unroll
        for (int j = 0; j < 4; ++j) Ws4[tid + 256 * j] = W4[tid + 256 * j];
    }
    const int tile0 = blockIdx.x * 128;
    {
        const int lr = tid >> 4;
        const int c4 = (tid & 15) * 4;
#pragma unroll
        for (int i = 0; i < 8; ++i) {
            int row = lr + 16 * i;
            int gr = tile0 + row;
            if (gr >= N) gr = N - 1;
            float4 v = *(const float4*)(x + (long long)gr * 64 + c4);
            xT[c4 + 0][row] = v.x;
            xT[c4 + 1][row] = v.y;
            xT[c4 + 2][row] = v.z;
            xT[c4 + 3][row] = v.w;
        }
    }
    __syncthreads();
    const int ri = tid >> 4;
    const int ci = tid & 15;
    float acc[8][4];
#pragma unroll
    for (int j = 0; j < 8; ++j)
#pragma unroll
        for (int c = 0; c < 4; ++c) acc[j][c] = 0.0f;
#pragma unroll 4
    for (int k = 0; k < 64; ++k) {
        float4 xa = *(const float4*)&xT[k][8 * ri];
        float4 xb = *(const float4*)&xT[k][8 * ri + 4];
        float4 wv = *(const float4*)&Ws[k * 64 + 4 * ci];
        float xr[8] = {xa.x, xa.y, xa.z, xa.w, xb.x, xb.y, xb.z, xb.w};
        float wc[4] = {wv.x, wv.y, wv.z, wv.w};
#pragma unroll
        for (int j = 0; j < 8; ++j)
#pragma unroll
            for (int c = 0; c < 4; ++c) acc[j][c] = fmaf(xr[j], wc[c], acc[j][c]);
    }
#pragma unroll
    for (int j = 0; j < 8; ++j) {
        int gr = tile0 + 8 * ri + j;
        if (gr < N) {
            float di = dinv[gr];
            __half2 h01 = __floats2half2_rn(acc[j][0] * di, acc[j][1] * di);
            __half2 h23 = __floats2half2_rn(acc[j][2] * di, acc[j][3] * di);
            uint2 u;
            u.x = *(unsigned int*)&h01;
            u.y = *(unsigned int*)&h23;
            *(uint2*)(xwsh + (long long)gr * 64 + 4 * ci) = u;  // 8B store
        }
    }
}

// fused bucket kernel: build the bucket's CSR in LDS (count -> scan -> rank
// place), then gather. 16-lane group owns one dst at a time (4 features/lane),
// 4-deep unrolled row loads (16 rows in flight per wave).
__global__ __launch_bounds__(512) void k_gfuse(const int* __restrict__ part,
                                               const int* __restrict__ gcur,
                                               const __half* __restrict__ xwsh,
                                               const float* __restrict__ b,
                                               const float* __restrict__ pa,
                                               float* __restrict__ out, int N) {
    __shared__ int cnt[128], inc[128], exc[128], rnk[128];
    __shared__ int lcsr[CAP];
    const int t = threadIdx.x;
    const int bb = blockIdx.x;
    const int beg = bb * CAP, end = gcur[bb];
    if (t < 128) { cnt[t] = 0; rnk[t] = 0; }
    __syncthreads();
    for (int i = beg + t; i < end; i += 512)
        atomicAdd(&cnt[(part[i] >> 17) & 127], 1);
    __syncthreads();
    if (t < 128) inc[t] = cnt[t];
    __syncthreads();
    for (int off = 1; off < 128; off <<= 1) {
        int v = (t < 128 && t >= off) ? inc[t - off] : 0;
        __syncthreads();
        if (t < 128) inc[t] += v;
        __syncthreads();
    }
    if (t < 128) exc[t] = inc[t] - cnt[t];
    __syncthreads();
    for (int i = beg + t; i < end; i += 512) {
        int v = part[i];
        int dl = (v >> 17) & 127;
        int r = atomicAdd(&rnk[dl], 1);
        lcsr[exc[dl] + r] = v & 0x1FFFF;
    }
    __syncthreads();

    const int lane = t & 63;
    const int g = lane >> 4;        // group 0..3 within wave
    const int fl = lane & 15;       // feature quad
    const int wib = t >> 6;         // wave 0..7
    const int q = wib * 4 + g;      // group 0..31 in block
    const float slope = pa[0];
    const float4 b4 = ((const float4*)b)[fl];
    const int tile0 = bb * 128;

    for (int dl = q; dl < 128; dl += 32) {
        int d = tile0 + dl;
        if (d >= N) break;
        const int jb = exc[dl];
        const int n = cnt[dl];
        float ax = 0.f, ay = 0.f, az = 0.f, aw = 0.f;
        int j = 0;
        for (; j + 3 < n; j += 4) {
            int s0 = lcsr[jb + j],     s1 = lcsr[jb + j + 1];
            int s2 = lcsr[jb + j + 2], s3 = lcsr[jb + j + 3];
            uint2 u0 = *(const uint2*)(xwsh + (long long)s0 * 64 + 4 * fl);
            uint2 u1 = *(const uint2*)(xwsh + (long long)s1 * 64 + 4 * fl);
            uint2 u2 = *(const uint2*)(xwsh + (long long)s2 * 64 + 4 * fl);
            uint2 u3 = *(const uint2*)(xwsh + (long long)s3 * 64 + 4 * fl);
            float2 a01 = __half22float2(*(const __half2*)&u0.x);
            float2 a23 = __half22float2(*(const __half2*)&u0.y);
            float2 b01 = __half22float2(*(const __half2*)&u1.x);
            float2 b23 = __half22float2(*(const __half2*)&u1.y);
            float2 c01 = __half22float2(*(const __half2*)&u2.x);
            float2 c23 = __half22float2(*(const __half2*)&u2.y);
            float2 d01 = __half22float2(*(const __half2*)&u3.x);
            float2 d23 = __half22float2(*(const __half2*)&u3.y);
            ax += (a01.x + b01.x) + (c01.x + d01.x);
            ay += (a01.y + b01.y) + (c01.y + d01.y);
            az += (a23.x + b23.x) + (c23.x + d23.x);
            aw += (a23.y + b23.y) + (c23.y + d23.y);
        }
        for (; j < n; ++j) {
            int s = lcsr[jb + j];
            uint2 u = *(const uint2*)(xwsh + (long long)s * 64 + 4 * fl);
            float2 f01 = __half22float2(*(const __half2*)&u.x);
            float2 f23 = __half22float2(*(const __half2*)&u.y);
            ax += f01.x; ay += f01.y; az += f23.x; aw += f23.y;
        }
        uint2 u = *(const uint2*)(xwsh + (long long)d * 64 + 4 * fl);  // self
        float2 s01 = __half22float2(*(const __half2*)&u.x);
        float2 s23 = __half22float2(*(const __half2*)&u.y);
        float di = rsqrtf((float)n + 1.0f);
        float4 v;
        v.x = di * (ax + s01.x) + b4.x;
        v.y = di * (ay + s01.y) + b4.y;
        v.z = di * (az + s23.x) + b4.z;
        v.w = di * (aw + s23.y) + b4.w;
        v.x = v.x >= 0.f ? v.x : slope * v.x;
        v.y = v.y >= 0.f ? v.y : slope * v.y;
        v.z = v.z >= 0.f ? v.z : slope * v.z;
        v.w = v.w >= 0.f ? v.w : slope * v.w;
        *(float4*)(out + (long long)d * 64 + 4 * fl) = v;
    }
}

extern "C" void kernel_launch(void* const* d_in, const int* in_sizes, int n_in,
                              void* d_out, int out_size, void* d_ws, size_t ws_size,
                              hipStream_t stream) {
    const float* x  = (const float*)d_in[0];
    const int*   ei = (const int*)d_in[1];
    const float* W  = (const float*)d_in[2];
    const float* b  = (const float*)d_in[3];
    const float* pa = (const float*)d_in[4];
    float* out = (float*)d_out;

    const int N = in_sizes[0] / 64;
    const long long E = (long long)in_sizes[1] / 2;
    const int nbuk = (N + 127) >> 7;           // 782 for N=100k (<= NBUK_MAX)
    const int chunk = iceil(E, NSCAT);

    char* ws = (char*)d_ws;
    size_t o = 0;
    int*    flag  = (int*)(ws + o);   o += 256;
    int*    gcur  = (int*)(ws + o);   o += ((size_t)nbuk * 4 + 255) & ~(size_t)255;
    float*  dinv  = (float*)(ws + o); o += ((size_t)N * 4 + 255) & ~(size_t)255;
    int*    part  = (int*)(ws + o);   o += ((size_t)nbuk * CAP * 4 + 255) & ~(size_t)255;
    __half* xwsh  = (__half*)(ws + o);  // N*64*2 = 12.8 MB; total ~26 MB

    k_detect<<<1, 256, 0, stream>>>(ei, (long long)in_sizes[1], flag, gcur, nbuk);
    k_scat<<<NSCAT, 256, 0, stream>>>(ei, flag, gcur, part, E, nbuk, chunk);
    k_cnt<<<nbuk, 256, 0, stream>>>(part, gcur, dinv, N);
    k_gemm<<<iceil(N, 128), 256, 0, stream>>>(x, W, dinv, xwsh, N);
    k_gfuse<<<nbuk, 512, 0, stream>>>(part, gcur, xwsh, b, pa, out, N);
}

// Round 16
// 91.375 us; speedup vs baseline: 1.8756x; 1.1269x over previous
//
#include <hip/hip_runtime.h>
#include <hip/hip_fp16.h>

// GCNConv (self-loops, symmetric norm) + bias + PReLU, fp32, N=100k, D=64, E=1.6M.
//
// Padded-bucket front end + fused (LDS-CSR build + gather):
//   1. k_detect: edge_index storage (int64 vs int32); init bucket cursors
//   2. k_scat:   single-read register-buffered pass; LDS count -> one global
//                atomicAdd per (block,bucket) -> LDS-rank write of
//                (dst&127)<<17|src into padded part[]
//   3. k_cnt:    per-bucket LDS count of 128 dsts -> dinv  (gemm needs it)
//   4. k_gemm:   xwsh = fp16((x @ W) * dinv[row])   (LDS-tiled, 128 rows/block)
//   5. k_gfuse:  per-bucket: count -> scan -> rank-place csr in LDS (16KB),
//                then 4-deep unrolled gather from LDS indices; fused epilogue.

static inline int iceil(long long a, int b) { return (int)((a + (long long)b - 1) / b); }

#define CAP 4096          // padded slots per 128-dst bucket (mean fill ~2046)
#define NBUK_MAX 1024     // supports N <= 131072
#define SCTH 1024         // scatter block threads
#define BUFK 8            // edges buffered per thread (chunk <= SCTH*BUFK)

__global__ void k_detect(const int* __restrict__ ei, long long n_i32_min,
                         int* __restrict__ flag, int* __restrict__ gcur, int nbuk) {
    __shared__ int nz;
    if (threadIdx.x == 0) nz = 0;
    __syncthreads();
    long long half = n_i32_min >> 1;
    long long step = half / 4096;
    if (step == 0) step = 1;
    for (int t = threadIdx.x; t < 4096; t += blockDim.x) {
        long long k = (long long)t * step;
        if (k < half && ei[2 * k + 1] != 0) nz = 1;  // benign race
    }
    for (int b = threadIdx.x; b < nbuk; b += blockDim.x) gcur[b] = b * CAP;
    __syncthreads();
    if (threadIdx.x == 0) *flag = nz ? 1 : 2;
}

// single-READ scatter: buffer <=BUFK edges in registers, LDS count, one global
// reserve atomic per nonempty (block,bucket), LDS-rank place from registers.
__global__ __launch_bounds__(SCTH) void k_scat(const int* __restrict__ ei,
                                               const int* __restrict__ flag,
                                               int* __restrict__ gcur,
                                               int* __restrict__ part,
                                               long long E, int nbuk, int chunk) {
    __shared__ int hist[NBUK_MAX];
    __shared__ int sbase[NBUK_MAX];
    const int t = threadIdx.x;
    for (int i = t; i < nbuk; i += SCTH) hist[i] = 0;
    __syncthreads();
    const int st = *flag;
    const long long beg = (long long)blockIdx.x * chunk;
    long long end = beg + chunk; if (end > E) end = E;

    int bs[BUFK], bd[BUFK];
#pragma unroll
    for (int kk = 0; kk < BUFK; ++kk) {
        long long e = beg + t + (long long)kk * SCTH;
        bool v = e < end;
        bs[kk] = v ? ei[e * st] : 0;
        bd[kk] = v ? ei[(E + e) * st] : -1;
    }
#pragma unroll
    for (int kk = 0; kk < BUFK; ++kk)
        if (bd[kk] >= 0) atomicAdd(&hist[bd[kk] >> 7], 1);
    __syncthreads();
    for (int i = t; i < nbuk; i += SCTH) {
        int c = hist[i];
        sbase[i] = c ? atomicAdd(&gcur[i], c) : 0;
        hist[i] = 0;  // reuse as rank counter
    }
    __syncthreads();
#pragma unroll
    for (int kk = 0; kk < BUFK; ++kk) {
        if (bd[kk] >= 0) {
            int b = bd[kk] >> 7;
            int r = atomicAdd(&hist[b], 1);
            part[sbase[b] + r] = ((bd[kk] & 127) << 17) | bs[kk];  // s < 2^17
        }
    }
}

// per-bucket count of 128 dsts -> dinv (consumed by gemm)
__global__ __launch_bounds__(256) void k_cnt(const int* __restrict__ part,
                                             const int* __restrict__ gcur,
                                             float* __restrict__ dinv, int N) {
    __shared__ int cnt[128];
    const int t = threadIdx.x;
    if (t < 128) cnt[t] = 0;
    __syncthreads();
    const int beg = blockIdx.x * CAP, end = gcur[blockIdx.x];
    for (int i = beg + t; i < end; i += 256)
        atomicAdd(&cnt[(part[i] >> 17) & 127], 1);
    __syncthreads();
    if (t < 128) {
        int d = blockIdx.x * 128 + t;
        if (d < N) dinv[d] = rsqrtf((float)cnt[t] + 1.0f);  // +1 self loop
    }
}

// xwsh = fp16((x @ W) * dinv[row]).  LDS-tiled, coalesced loads, 8x4 per thread.
__global__ __launch_bounds__(256) void k_gemm(const float* __restrict__ x,
                                              const float* __restrict__ W,
                                              const float* __restrict__ dinv,
                                              __half* __restrict__ xwsh, int N) {
    __shared__ float Ws[64 * 64];
    __shared__ float xT[64][132];
    const int tid = threadIdx.x;
    {
        const float4* W4 = (const float4*)W;
        float4* Ws4 = (float4*)Ws;
#pragma unroll
        for (int j = 0; j < 4; ++j) Ws4[tid + 256 * j] = W4[tid + 256 * j];
    }
    const int tile0 = blockIdx.x * 128;
    {
        const int lr = tid >> 4;
        const int c4 = (tid & 15) * 4;
#pragma unroll
        for (int i = 0; i < 8; ++i) {
            int row = lr + 16 * i;
            int gr = tile0 + row;
            if (gr >= N) gr = N - 1;
            float4 v = *(const float4*)(x + (long long)gr * 64 + c4);
            xT[c4 + 0][row] = v.x;
            xT[c4 + 1][row] = v.y;
            xT[c4 + 2][row] = v.z;
            xT[c4 + 3][row] = v.w;
        }
    }
    __syncthreads();
    const int ri = tid >> 4;
    const int ci = tid & 15;
    float acc[8][4];
#pragma unroll
    for (int j = 0; j < 8; ++j)
#pragma unroll
        for (int c = 0; c < 4; ++c) acc[j][c] = 0.0f;
#pragma unroll 4
    for (int k = 0; k < 64; ++k) {
        float4 xa = *(const float4*)&xT[k][8 * ri];
        float4 xb = *(const float4*)&xT[k][8 * ri + 4];
        float4 wv = *(const float4*)&Ws[k * 64 + 4 * ci];
        float xr[8] = {xa.x, xa.y, xa.z, xa.w, xb.x, xb.y, xb.z, xb.w};
        float wc[4] = {wv.x, wv.y, wv.z, wv.w};
#pragma unroll
        for (int j = 0; j < 8; ++j)
#pragma unroll
            for (int c = 0; c < 4; ++c) acc[j][c] = fmaf(xr[j], wc[c], acc[j][c]);
    }
#pragma unroll
    for (int j = 0; j < 8; ++j) {
        int gr = tile0 + 8 * ri + j;
        if (gr < N) {
            float di = dinv[gr];
            __half2 h01 = __floats2half2_rn(acc[j][0] * di, acc[j][1] * di);
            __half2 h23 = __floats2half2_rn(acc[j][2] * di, acc[j][3] * di);
            uint2 u;
            u.x = *(unsigned int*)&h01;
            u.y = *(unsigned int*)&h23;
            *(uint2*)(xwsh + (long long)gr * 64 + 4 * ci) = u;  // 8B store
        }
    }
}

// fused bucket kernel: build the bucket's CSR in LDS (count -> scan -> rank
// place), then gather. 16-lane group owns one dst at a time (4 features/lane),
// 4-deep unrolled row loads (16 rows in flight per wave).
__global__ __launch_bounds__(512) void k_gfuse(const int* __restrict__ part,
                                               const int* __restrict__ gcur,
                                               const __half* __restrict__ xwsh,
                                               const float* __restrict__ b,
                                               const float* __restrict__ pa,
                                               float* __restrict__ out, int N) {
    __shared__ int cnt[128], inc[128], exc[128], rnk[128];
    __shared__ int lcsr[CAP];
    const int t = threadIdx.x;
    const int bb = blockIdx.x;
    const int beg = bb * CAP, end = gcur[bb];
    if (t < 128) { cnt[t] = 0; rnk[t] = 0; }
    __syncthreads();
    for (int i = beg + t; i < end; i += 512)
        atomicAdd(&cnt[(part[i] >> 17) & 127], 1);
    __syncthreads();
    if (t < 128) inc[t] = cnt[t];
    __syncthreads();
    for (int off = 1; off < 128; off <<= 1) {
        int v = (t < 128 && t >= off) ? inc[t - off] : 0;
        __syncthreads();
        if (t < 128) inc[t] += v;
        __syncthreads();
    }
    if (t < 128) exc[t] = inc[t] - cnt[t];
    __syncthreads();
    for (int i = beg + t; i < end; i += 512) {
        int v = part[i];
        int dl = (v >> 17) & 127;
        int r = atomicAdd(&rnk[dl], 1);
        lcsr[exc[dl] + r] = v & 0x1FFFF;
    }
    __syncthreads();

    const int lane = t & 63;
    const int g = lane >> 4;        // group 0..3 within wave
    const int fl = lane & 15;       // feature quad
    const int wib = t >> 6;         // wave 0..7
    const int q = wib * 4 + g;      // group 0..31 in block
    const float slope = pa[0];
    const float4 b4 = ((const float4*)b)[fl];
    const int tile0 = bb * 128;

    for (int dl = q; dl < 128; dl += 32) {
        int d = tile0 + dl;
        if (d >= N) break;
        const int jb = exc[dl];
        const int n = cnt[dl];
        float ax = 0.f, ay = 0.f, az = 0.f, aw = 0.f;
        int j = 0;
        for (; j + 3 < n; j += 4) {
            int s0 = lcsr[jb + j],     s1 = lcsr[jb + j + 1];
            int s2 = lcsr[jb + j + 2], s3 = lcsr[jb + j + 3];
            uint2 u0 = *(const uint2*)(xwsh + (long long)s0 * 64 + 4 * fl);
            uint2 u1 = *(const uint2*)(xwsh + (long long)s1 * 64 + 4 * fl);
            uint2 u2 = *(const uint2*)(xwsh + (long long)s2 * 64 + 4 * fl);
            uint2 u3 = *(const uint2*)(xwsh + (long long)s3 * 64 + 4 * fl);
            float2 a01 = __half22float2(*(const __half2*)&u0.x);
            float2 a23 = __half22float2(*(const __half2*)&u0.y);
            float2 b01 = __half22float2(*(const __half2*)&u1.x);
            float2 b23 = __half22float2(*(const __half2*)&u1.y);
            float2 c01 = __half22float2(*(const __half2*)&u2.x);
            float2 c23 = __half22float2(*(const __half2*)&u2.y);
            float2 d01 = __half22float2(*(const __half2*)&u3.x);
            float2 d23 = __half22float2(*(const __half2*)&u3.y);
            ax += (a01.x + b01.x) + (c01.x + d01.x);
            ay += (a01.y + b01.y) + (c01.y + d01.y);
            az += (a23.x + b23.x) + (c23.x + d23.x);
            aw += (a23.y + b23.y) + (c23.y + d23.y);
        }
        for (; j < n; ++j) {
            int s = lcsr[jb + j];
            uint2 u = *(const uint2*)(xwsh + (long long)s * 64 + 4 * fl);
            float2 f01 = __half22float2(*(const __half2*)&u.x);
            float2 f23 = __half22float2(*(const __half2*)&u.y);
            ax += f01.x; ay += f01.y; az += f23.x; aw += f23.y;
        }
        uint2 u = *(const uint2*)(xwsh + (long long)d * 64 + 4 * fl);  // self
        float2 s01 = __half22float2(*(const __half2*)&u.x);
        float2 s23 = __half22float2(*(const __half2*)&u.y);
        float di = rsqrtf((float)n + 1.0f);
        float4 v;
        v.x = di * (ax + s01.x) + b4.x;
        v.y = di * (ay + s01.y) + b4.y;
        v.z = di * (az + s23.x) + b4.z;
        v.w = di * (aw + s23.y) + b4.w;
        v.x = v.x >= 0.f ? v.x : slope * v.x;
        v.y = v.y >= 0.f ? v.y : slope * v.y;
        v.z = v.z >= 0.f ? v.z : slope * v.z;
        v.w = v.w >= 0.f ? v.w : slope * v.w;
        *(float4*)(out + (long long)d * 64 + 4 * fl) = v;
    }
}

extern "C" void kernel_launch(void* const* d_in, const int* in_sizes, int n_in,
                              void* d_out, int out_size, void* d_ws, size_t ws_size,
                              hipStream_t stream) {
    const float* x  = (const float*)d_in[0];
    const int*   ei = (const int*)d_in[1];
    const float* W  = (const float*)d_in[2];
    const float* b  = (const float*)d_in[3];
    const float* pa = (const float*)d_in[4];
    float* out = (float*)d_out;

    const int N = in_sizes[0] / 64;
    const long long E = (long long)in_sizes[1] / 2;
    const int nbuk = (N + 127) >> 7;           // 782 for N=100k (<= NBUK_MAX)
    // scatter blocks: each block buffers chunk <= SCTH*BUFK edges in registers
    int nscat = iceil(E, SCTH * BUFK);
    if (nscat < 256) nscat = 256;              // keep all CUs busy
    const int chunk = iceil(E, nscat);

    char* ws = (char*)d_ws;
    size_t o = 0;
    int*    flag  = (int*)(ws + o);   o += 256;
    int*    gcur  = (int*)(ws + o);   o += ((size_t)nbuk * 4 + 255) & ~(size_t)255;
    float*  dinv  = (float*)(ws + o); o += ((size_t)N * 4 + 255) & ~(size_t)255;
    int*    part  = (int*)(ws + o);   o += ((size_t)nbuk * CAP * 4 + 255) & ~(size_t)255;
    __half* xwsh  = (__half*)(ws + o);  // N*64*2 = 12.8 MB; total ~26 MB

    k_detect<<<1, 256, 0, stream>>>(ei, (long long)in_sizes[1], flag, gcur, nbuk);
    k_scat<<<nscat, SCTH, 0, stream>>>(ei, flag, gcur, part, E, nbuk, chunk);
    k_cnt<<<nbuk, 256, 0, stream>>>(part, gcur, dinv, N);
    k_gemm<<<iceil(N, 128), 256, 0, stream>>>(x, W, dinv, xwsh, N);
    k_gfuse<<<nbuk, 512, 0, stream>>>(part, gcur, xwsh, b, pa, out, N);
}

// Round 17
// 87.006 us; speedup vs baseline: 1.9698x; 1.0502x over previous
//
#include <hip/hip_runtime.h>
#include <hip/hip_fp16.h>

// GCNConv (self-loops, symmetric norm) + bias + PReLU, fp32, N=100k, D=64, E=1.6M.
//
// Padded-bucket front end + meta (count+scan hoisted) + fused LDS-CSR gather:
//   1. k_detect: edge_index storage (int64 vs int32); init bucket cursors
//   2. k_scat:   single-read register-buffered pass; LDS count -> one global
//                atomicAdd per (block,bucket) -> LDS-rank write of
//                (dst&127)<<17|src into padded part[]
//   3. k_meta:   per-bucket LDS count of 128 dsts + scan -> dinv (for gemm)
//                and per-dst (cnt,exc) meta table (for gfuse)
//   4. k_gemm:   xwsh = fp16((x @ W) * dinv[row])   (LDS-tiled, 128 rows/block)
//   5. k_gfuse:  per-bucket: rank-place csr in LDS using meta, then 4-deep
//                unrolled gather from LDS indices; fused epilogue.

static inline int iceil(long long a, int b) { return (int)((a + (long long)b - 1) / b); }

#define CAP 4096          // padded slots per 128-dst bucket (mean fill ~2046)
#define NBUK_MAX 1024     // supports N <= 131072
#define SCTH 1024         // scatter block threads
#define BUFK 8            // edges buffered per thread (chunk <= SCTH*BUFK)

__global__ void k_detect(const int* __restrict__ ei, long long n_i32_min,
                         int* __restrict__ flag, int* __restrict__ gcur, int nbuk) {
    __shared__ int nz;
    if (threadIdx.x == 0) nz = 0;
    __syncthreads();
    long long half = n_i32_min >> 1;
    long long step = half / 1024;
    if (step == 0) step = 1;
    for (int t = threadIdx.x; t < 1024; t += blockDim.x) {
        long long k = (long long)t * step;
        if (k < half && ei[2 * k + 1] != 0) nz = 1;  // benign race
    }
    for (int b = threadIdx.x; b < nbuk; b += blockDim.x) gcur[b] = b * CAP;
    __syncthreads();
    if (threadIdx.x == 0) *flag = nz ? 1 : 2;
}

// single-READ scatter: buffer <=BUFK edges in registers, LDS count, one global
// reserve atomic per nonempty (block,bucket), LDS-rank place from registers.
__global__ __launch_bounds__(SCTH) void k_scat(const int* __restrict__ ei,
                                               const int* __restrict__ flag,
                                               int* __restrict__ gcur,
                                               int* __restrict__ part,
                                               long long E, int nbuk, int chunk) {
    __shared__ int hist[NBUK_MAX];
    __shared__ int sbase[NBUK_MAX];
    const int t = threadIdx.x;
    for (int i = t; i < nbuk; i += SCTH) hist[i] = 0;
    __syncthreads();
    const int st = *flag;
    const long long beg = (long long)blockIdx.x * chunk;
    long long end = beg + chunk; if (end > E) end = E;

    int bs[BUFK], bd[BUFK];
#pragma unroll
    for (int kk = 0; kk < BUFK; ++kk) {
        long long e = beg + t + (long long)kk * SCTH;
        bool v = e < end;
        bs[kk] = v ? ei[e * st] : 0;
        bd[kk] = v ? ei[(E + e) * st] : -1;
    }
#pragma unroll
    for (int kk = 0; kk < BUFK; ++kk)
        if (bd[kk] >= 0) atomicAdd(&hist[bd[kk] >> 7], 1);
    __syncthreads();
    for (int i = t; i < nbuk; i += SCTH) {
        int c = hist[i];
        sbase[i] = c ? atomicAdd(&gcur[i], c) : 0;
        hist[i] = 0;  // reuse as rank counter
    }
    __syncthreads();
#pragma unroll
    for (int kk = 0; kk < BUFK; ++kk) {
        if (bd[kk] >= 0) {
            int b = bd[kk] >> 7;
            int r = atomicAdd(&hist[b], 1);
            part[sbase[b] + r] = ((bd[kk] & 127) << 17) | bs[kk];  // s < 2^17
        }
    }
}

// per-bucket count + scan: dinv (for gemm) and (cnt,exc) meta (for gfuse)
__global__ __launch_bounds__(512) void k_meta(const int* __restrict__ part,
                                              const int* __restrict__ gcur,
                                              float* __restrict__ dinv,
                                              int2* __restrict__ meta, int N) {
    __shared__ int cnt[128], inc[128];
    const int t = threadIdx.x;
    if (t < 128) cnt[t] = 0;
    __syncthreads();
    const int beg = blockIdx.x * CAP, end = gcur[blockIdx.x];
    for (int i = beg + t; i < end; i += 512)
        atomicAdd(&cnt[(part[i] >> 17) & 127], 1);
    __syncthreads();
    if (t < 128) inc[t] = cnt[t];
    __syncthreads();
    for (int off = 1; off < 128; off <<= 1) {
        int v = (t < 128 && t >= off) ? inc[t - off] : 0;
        __syncthreads();
        if (t < 128) inc[t] += v;
        __syncthreads();
    }
    if (t < 128) {
        int d = blockIdx.x * 128 + t;
        if (d < N) {
            dinv[d] = rsqrtf((float)cnt[t] + 1.0f);      // +1 self loop
            meta[d] = make_int2(cnt[t], inc[t] - cnt[t]); // (count, excl offset)
        }
    }
}

// xwsh = fp16((x @ W) * dinv[row]).  LDS-tiled, coalesced loads, 8x4 per thread.
__global__ __launch_bounds__(256) void k_gemm(const float* __restrict__ x,
                                              const float* __restrict__ W,
                                              const float* __restrict__ dinv,
                                              __half* __restrict__ xwsh, int N) {
    __shared__ float Ws[64 * 64];
    __shared__ float xT[64][132];
    const int tid = threadIdx.x;
    {
        const float4* W4 = (const float4*)W;
        float4* Ws4 = (float4*)Ws;
#pragma unroll
        for (int j = 0; j < 4; ++j) Ws4[tid + 256 * j] = W4[tid + 256 * j];
    }
    const int tile0 = blockIdx.x * 128;
    {
        const int lr = tid >> 4;
        const int c4 = (tid & 15) * 4;
#pragma unroll
        for (int i = 0; i < 8; ++i) {
            int row = lr + 16 * i;
            int gr = tile0 + row;
            if (gr >= N) gr = N - 1;
            float4 v = *(const float4*)(x + (long long)gr * 64 + c4);
            xT[c4 + 0][row] = v.x;
            xT[c4 + 1][row] = v.y;
            xT[c4 + 2][row] = v.z;
            xT[c4 + 3][row] = v.w;
        }
    }
    __syncthreads();
    const int ri = tid >> 4;
    const int ci = tid & 15;
    float acc[8][4];
#pragma unroll
    for (int j = 0; j < 8; ++j)
#pragma unroll
        for (int c = 0; c < 4; ++c) acc[j][c] = 0.0f;
#pragma unroll 4
    for (int k = 0; k < 64; ++k) {
        float4 xa = *(const float4*)&xT[k][8 * ri];
        float4 xb = *(const float4*)&xT[k][8 * ri + 4];
        float4 wv = *(const float4*)&Ws[k * 64 + 4 * ci];
        float xr[8] = {xa.x, xa.y, xa.z, xa.w, xb.x, xb.y, xb.z, xb.w};
        float wc[4] = {wv.x, wv.y, wv.z, wv.w};
#pragma unroll
        for (int j = 0; j < 8; ++j)
#pragma unroll
            for (int c = 0; c < 4; ++c) acc[j][c] = fmaf(xr[j], wc[c], acc[j][c]);
    }
#pragma unroll
    for (int j = 0; j < 8; ++j) {
        int gr = tile0 + 8 * ri + j;
        if (gr < N) {
            float di = dinv[gr];
            __half2 h01 = __floats2half2_rn(acc[j][0] * di, acc[j][1] * di);
            __half2 h23 = __floats2half2_rn(acc[j][2] * di, acc[j][3] * di);
            uint2 u;
            u.x = *(unsigned int*)&h01;
            u.y = *(unsigned int*)&h23;
            *(uint2*)(xwsh + (long long)gr * 64 + 4 * ci) = u;  // 8B store
        }
    }
}

// fused bucket kernel: rank-place csr in LDS (counts/offsets from meta), then
// gather. 16-lane group owns one dst at a time (4 features/lane), 4-deep
// unrolled row loads (16 rows in flight per wave).
__global__ __launch_bounds__(512) void k_gfuse(const int* __restrict__ part,
                                               const int* __restrict__ gcur,
                                               const int2* __restrict__ meta,
                                               const __half* __restrict__ xwsh,
                                               const float* __restrict__ b,
                                               const float* __restrict__ pa,
                                               float* __restrict__ out, int N) {
    __shared__ int cnt[128], exc[128], rnk[128];
    __shared__ int lcsr[CAP];
    const int t = threadIdx.x;
    const int bb = blockIdx.x;
    const int beg = bb * CAP, end = gcur[bb];
    const int tile0 = bb * 128;
    if (t < 128) {
        int d = tile0 + t;
        int2 m = (d < N) ? meta[d] : make_int2(0, 0);
        cnt[t] = m.x;
        exc[t] = m.y;
        rnk[t] = 0;
    }
    __syncthreads();
    for (int i = beg + t; i < end; i += 512) {
        int v = part[i];
        int dl = (v >> 17) & 127;
        int r = atomicAdd(&rnk[dl], 1);
        lcsr[exc[dl] + r] = v & 0x1FFFF;
    }
    __syncthreads();

    const int lane = t & 63;
    const int g = lane >> 4;        // group 0..3 within wave
    const int fl = lane & 15;       // feature quad
    const int wib = t >> 6;         // wave 0..7
    const int q = wib * 4 + g;      // group 0..31 in block
    const float slope = pa[0];
    const float4 b4 = ((const float4*)b)[fl];

    for (int dl = q; dl < 128; dl += 32) {
        int d = tile0 + dl;
        if (d >= N) break;
        const int jb = exc[dl];
        const int n = cnt[dl];
        float ax = 0.f, ay = 0.f, az = 0.f, aw = 0.f;
        int j = 0;
        for (; j + 3 < n; j += 4) {
            int s0 = lcsr[jb + j],     s1 = lcsr[jb + j + 1];
            int s2 = lcsr[jb + j + 2], s3 = lcsr[jb + j + 3];
            uint2 u0 = *(const uint2*)(xwsh + (long long)s0 * 64 + 4 * fl);
            uint2 u1 = *(const uint2*)(xwsh + (long long)s1 * 64 + 4 * fl);
            uint2 u2 = *(const uint2*)(xwsh + (long long)s2 * 64 + 4 * fl);
            uint2 u3 = *(const uint2*)(xwsh + (long long)s3 * 64 + 4 * fl);
            float2 a01 = __half22float2(*(const __half2*)&u0.x);
            float2 a23 = __half22float2(*(const __half2*)&u0.y);
            float2 b01 = __half22float2(*(const __half2*)&u1.x);
            float2 b23 = __half22float2(*(const __half2*)&u1.y);
            float2 c01 = __half22float2(*(const __half2*)&u2.x);
            float2 c23 = __half22float2(*(const __half2*)&u2.y);
            float2 d01 = __half22float2(*(const __half2*)&u3.x);
            float2 d23 = __half22float2(*(const __half2*)&u3.y);
            ax += (a01.x + b01.x) + (c01.x + d01.x);
            ay += (a01.y + b01.y) + (c01.y + d01.y);
            az += (a23.x + b23.x) + (c23.x + d23.x);
            aw += (a23.y + b23.y) + (c23.y + d23.y);
        }
        for (; j < n; ++j) {
            int s = lcsr[jb + j];
            uint2 u = *(const uint2*)(xwsh + (long long)s * 64 + 4 * fl);
            float2 f01 = __half22float2(*(const __half2*)&u.x);
            float2 f23 = __half22float2(*(const __half2*)&u.y);
            ax += f01.x; ay += f01.y; az += f23.x; aw += f23.y;
        }
        uint2 u = *(const uint2*)(xwsh + (long long)d * 64 + 4 * fl);  // self
        float2 s01 = __half22float2(*(const __half2*)&u.x);
        float2 s23 = __half22float2(*(const __half2*)&u.y);
        float di = rsqrtf((float)n + 1.0f);
        float4 v;
        v.x = di * (ax + s01.x) + b4.x;
        v.y = di * (ay + s01.y) + b4.y;
        v.z = di * (az + s23.x) + b4.z;
        v.w = di * (aw + s23.y) + b4.w;
        v.x = v.x >= 0.f ? v.x : slope * v.x;
        v.y = v.y >= 0.f ? v.y : slope * v.y;
        v.z = v.z >= 0.f ? v.z : slope * v.z;
        v.w = v.w >= 0.f ? v.w : slope * v.w;
        *(float4*)(out + (long long)d * 64 + 4 * fl) = v;
    }
}

extern "C" void kernel_launch(void* const* d_in, const int* in_sizes, int n_in,
                              void* d_out, int out_size, void* d_ws, size_t ws_size,
                              hipStream_t stream) {
    const float* x  = (const float*)d_in[0];
    const int*   ei = (const int*)d_in[1];
    const float* W  = (const float*)d_in[2];
    const float* b  = (const float*)d_in[3];
    const float* pa = (const float*)d_in[4];
    float* out = (float*)d_out;

    const int N = in_sizes[0] / 64;
    const long long E = (long long)in_sizes[1] / 2;
    const int nbuk = (N + 127) >> 7;           // 782 for N=100k (<= NBUK_MAX)
    int nscat = iceil(E, SCTH * BUFK);
    if (nscat < 256) nscat = 256;              // keep all CUs busy
    const int chunk = iceil(E, nscat);

    char* ws = (char*)d_ws;
    size_t o = 0;
    int*    flag  = (int*)(ws + o);   o += 256;
    int*    gcur  = (int*)(ws + o);   o += ((size_t)nbuk * 4 + 255) & ~(size_t)255;
    float*  dinv  = (float*)(ws + o); o += ((size_t)N * 4 + 255) & ~(size_t)255;
    int2*   meta  = (int2*)(ws + o);  o += ((size_t)N * 8 + 255) & ~(size_t)255;
    int*    part  = (int*)(ws + o);   o += ((size_t)nbuk * CAP * 4 + 255) & ~(size_t)255;
    __half* xwsh  = (__half*)(ws + o);  // N*64*2 = 12.8 MB; total ~27 MB

    k_detect<<<1, 256, 0, stream>>>(ei, (long long)in_sizes[1], flag, gcur, nbuk);
    k_scat<<<nscat, SCTH, 0, stream>>>(ei, flag, gcur, part, E, nbuk, chunk);
    k_meta<<<nbuk, 512, 0, stream>>>(part, gcur, dinv, meta, N);
    k_gemm<<<iceil(N, 128), 256, 0, stream>>>(x, W, dinv, xwsh, N);
    k_gfuse<<<nbuk, 512, 0, stream>>>(part, gcur, meta, xwsh, b, pa, out, N);
}

// Round 18
// 86.733 us; speedup vs baseline: 1.9760x; 1.0031x over previous
//
#include <hip/hip_runtime.h>
#include <hip/hip_fp16.h>

// GCNConv (self-loops, symmetric norm) + bias + PReLU, fp32, N=100k, D=64, E=1.6M.
//
// Padded-bucket front end; meta fused into gemm; fused LDS-CSR gather:
//   1. k_detect:   edge_index storage (int64 vs int32); init bucket cursors
//   2. k_scat:     single-read register-buffered pass; LDS count -> one global
//                  atomicAdd per (block,bucket) -> LDS-rank write of
//                  (dst&127)<<17|src into padded part[]
//   3. k_gemmmeta: block bb = bucket bb = row tile bb. Counts its part segment
//                  (128 dsts) + scan -> meta[d]=(cnt,exc) for gfuse, dinv in
//                  LDS; then xwsh = fp16((x @ W) * dinv[row]) (LDS-tiled).
//   4. k_gfuse:    per-bucket: rank-place csr in LDS using meta, then 8-deep
//                  unrolled gather from LDS indices; fused epilogue.

static inline int iceil(long long a, int b) { return (int)((a + (long long)b - 1) / b); }

#define CAP 4096          // padded slots per 128-dst bucket (mean fill ~2046)
#define NBUK_MAX 1024     // supports N <= 131072
#define SCTH 1024         // scatter block threads
#define BUFK 8            // edges buffered per thread (chunk <= SCTH*BUFK)

__global__ void k_detect(const int* __restrict__ ei, long long n_i32_min,
                         int* __restrict__ flag, int* __restrict__ gcur, int nbuk) {
    __shared__ int nz;
    if (threadIdx.x == 0) nz = 0;
    __syncthreads();
    long long half = n_i32_min >> 1;
    long long step = half / 1024;
    if (step == 0) step = 1;
    for (int t = threadIdx.x; t < 1024; t += blockDim.x) {
        long long k = (long long)t * step;
        if (k < half && ei[2 * k + 1] != 0) nz = 1;  // benign race
    }
    for (int b = threadIdx.x; b < nbuk; b += blockDim.x) gcur[b] = b * CAP;
    __syncthreads();
    if (threadIdx.x == 0) *flag = nz ? 1 : 2;
}

// single-READ scatter: buffer <=BUFK edges in registers, LDS count, one global
// reserve atomic per nonempty (block,bucket), LDS-rank place from registers.
__global__ __launch_bounds__(SCTH) void k_scat(const int* __restrict__ ei,
                                               const int* __restrict__ flag,
                                               int* __restrict__ gcur,
                                               int* __restrict__ part,
                                               long long E, int nbuk, int chunk) {
    __shared__ int hist[NBUK_MAX];
    __shared__ int sbase[NBUK_MAX];
    const int t = threadIdx.x;
    for (int i = t; i < nbuk; i += SCTH) hist[i] = 0;
    __syncthreads();
    const int st = *flag;
    const long long beg = (long long)blockIdx.x * chunk;
    long long end = beg + chunk; if (end > E) end = E;

    int bs[BUFK], bd[BUFK];
#pragma unroll
    for (int kk = 0; kk < BUFK; ++kk) {
        long long e = beg + t + (long long)kk * SCTH;
        bool v = e < end;
        bs[kk] = v ? ei[e * st] : 0;
        bd[kk] = v ? ei[(E + e) * st] : -1;
    }
#pragma unroll
    for (int kk = 0; kk < BUFK; ++kk)
        if (bd[kk] >= 0) atomicAdd(&hist[bd[kk] >> 7], 1);
    __syncthreads();
    for (int i = t; i < nbuk; i += SCTH) {
        int c = hist[i];
        sbase[i] = c ? atomicAdd(&gcur[i], c) : 0;
        hist[i] = 0;  // reuse as rank counter
    }
    __syncthreads();
#pragma unroll
    for (int kk = 0; kk < BUFK; ++kk) {
        if (bd[kk] >= 0) {
            int b = bd[kk] >> 7;
            int r = atomicAdd(&hist[b], 1);
            part[sbase[b] + r] = ((bd[kk] & 127) << 17) | bs[kk];  // s < 2^17
        }
    }
}

// fused meta + gemm: block bb handles bucket bb AND row tile bb (both 128 rows).
// Phase A: count part segment per dst + scan -> meta (for gfuse), dinv in LDS.
// Phase B: xwsh = fp16((x @ W) * dinvL[row]), LDS-tiled, 8x4 per thread.
__global__ __launch_bounds__(256) void k_gemmmeta(const int* __restrict__ part,
                                                  const int* __restrict__ gcur,
                                                  const float* __restrict__ x,
                                                  const float* __restrict__ W,
                                                  int2* __restrict__ meta,
                                                  __half* __restrict__ xwsh, int N) {
    __shared__ float Ws[64 * 64];
    __shared__ float xT[64][132];
    __shared__ int cnt[128], inc[128];
    __shared__ float dinvL[128];
    const int tid = threadIdx.x;
    const int bb = blockIdx.x;
    const int tile0 = bb * 128;

    if (tid < 128) cnt[tid] = 0;
    __syncthreads();

    // issue x/W staging (LDS writes, no dependency on cnt) interleaved with
    // the part count (different LDS regions; atomics vs plain writes ok)
    {
        const float4* W4 = (const float4*)W;
        float4* Ws4 = (float4*)Ws;
#pragma unroll
        for (int j = 0; j < 4; ++j) Ws4[tid + 256 * j] = W4[tid + 256 * j];
        const int lr = tid >> 4;
        const int c4 = (tid & 15) * 4;
#pragma unroll
        for (int i = 0; i < 8; ++i) {
            int row = lr + 16 * i;
            int gr = tile0 + row;
            if (gr >= N) gr = N - 1;
            float4 v = *(const float4*)(x + (long long)gr * 64 + c4);
            xT[c4 + 0][row] = v.x;
            xT[c4 + 1][row] = v.y;
            xT[c4 + 2][row] = v.z;
            xT[c4 + 3][row] = v.w;
        }
    }
    {
        const int beg = bb * CAP, end = gcur[bb];
        for (int i = beg + tid; i < end; i += 256)
            atomicAdd(&cnt[(part[i] >> 17) & 127], 1);
    }
    __syncthreads();
    if (tid < 128) inc[tid] = cnt[tid];
    __syncthreads();
    for (int off = 1; off < 128; off <<= 1) {
        int v = (tid < 128 && tid >= off) ? inc[tid - off] : 0;
        __syncthreads();
        if (tid < 128) inc[tid] += v;
        __syncthreads();
    }
    if (tid < 128) {
        dinvL[tid] = rsqrtf((float)cnt[tid] + 1.0f);  // +1 self loop
        int d = tile0 + tid;
        if (d < N) meta[d] = make_int2(cnt[tid], inc[tid] - cnt[tid]);
    }
    __syncthreads();

    const int ri = tid >> 4;
    const int ci = tid & 15;
    float acc[8][4];
#pragma unroll
    for (int j = 0; j < 8; ++j)
#pragma unroll
        for (int c = 0; c < 4; ++c) acc[j][c] = 0.0f;
#pragma unroll 4
    for (int k = 0; k < 64; ++k) {
        float4 xa = *(const float4*)&xT[k][8 * ri];
        float4 xb = *(const float4*)&xT[k][8 * ri + 4];
        float4 wv = *(const float4*)&Ws[k * 64 + 4 * ci];
        float xr[8] = {xa.x, xa.y, xa.z, xa.w, xb.x, xb.y, xb.z, xb.w};
        float wc[4] = {wv.x, wv.y, wv.z, wv.w};
#pragma unroll
        for (int j = 0; j < 8; ++j)
#pragma unroll
            for (int c = 0; c < 4; ++c) acc[j][c] = fmaf(xr[j], wc[c], acc[j][c]);
    }
#pragma unroll
    for (int j = 0; j < 8; ++j) {
        int gr = tile0 + 8 * ri + j;
        if (gr < N) {
            float di = dinvL[8 * ri + j];
            __half2 h01 = __floats2half2_rn(acc[j][0] * di, acc[j][1] * di);
            __half2 h23 = __floats2half2_rn(acc[j][2] * di, acc[j][3] * di);
            uint2 u;
            u.x = *(unsigned int*)&h01;
            u.y = *(unsigned int*)&h23;
            *(uint2*)(xwsh + (long long)gr * 64 + 4 * ci) = u;  // 8B store
        }
    }
}

// fused bucket kernel: rank-place csr in LDS (counts/offsets from meta), then
// gather. 16-lane group owns one dst at a time (4 features/lane), 8-deep
// unrolled row loads (32 rows in flight per wave).
__global__ __launch_bounds__(512) void k_gfuse(const int* __restrict__ part,
                                               const int* __restrict__ gcur,
                                               const int2* __restrict__ meta,
                                               const __half* __restrict__ xwsh,
                                               const float* __restrict__ b,
                                               const float* __restrict__ pa,
                                               float* __restrict__ out, int N) {
    __shared__ int cnt[128], exc[128], rnk[128];
    __shared__ int lcsr[CAP];
    const int t = threadIdx.x;
    const int bb = blockIdx.x;
    const int beg = bb * CAP, end = gcur[bb];
    const int tile0 = bb * 128;
    if (t < 128) {
        int d = tile0 + t;
        int2 m = (d < N) ? meta[d] : make_int2(0, 0);
        cnt[t] = m.x;
        exc[t] = m.y;
        rnk[t] = 0;
    }
    __syncthreads();
    for (int i = beg + t; i < end; i += 512) {
        int v = part[i];
        int dl = (v >> 17) & 127;
        int r = atomicAdd(&rnk[dl], 1);
        lcsr[exc[dl] + r] = v & 0x1FFFF;
    }
    __syncthreads();

    const int lane = t & 63;
    const int g = lane >> 4;        // group 0..3 within wave
    const int fl = lane & 15;       // feature quad
    const int wib = t >> 6;         // wave 0..7
    const int q = wib * 4 + g;      // group 0..31 in block
    const float slope = pa[0];
    const float4 b4 = ((const float4*)b)[fl];

    for (int dl = q; dl < 128; dl += 32) {
        int d = tile0 + dl;
        if (d >= N) break;
        const int jb = exc[dl];
        const int n = cnt[dl];
        float ax = 0.f, ay = 0.f, az = 0.f, aw = 0.f;
        int j = 0;
        for (; j + 7 < n; j += 8) {
            int s0 = lcsr[jb + j],     s1 = lcsr[jb + j + 1];
            int s2 = lcsr[jb + j + 2], s3 = lcsr[jb + j + 3];
            int s4 = lcsr[jb + j + 4], s5 = lcsr[jb + j + 5];
            int s6 = lcsr[jb + j + 6], s7 = lcsr[jb + j + 7];
            uint2 u0 = *(const uint2*)(xwsh + (long long)s0 * 64 + 4 * fl);
            uint2 u1 = *(const uint2*)(xwsh + (long long)s1 * 64 + 4 * fl);
            uint2 u2 = *(const uint2*)(xwsh + (long long)s2 * 64 + 4 * fl);
            uint2 u3 = *(const uint2*)(xwsh + (long long)s3 * 64 + 4 * fl);
            uint2 u4 = *(const uint2*)(xwsh + (long long)s4 * 64 + 4 * fl);
            uint2 u5 = *(const uint2*)(xwsh + (long long)s5 * 64 + 4 * fl);
            uint2 u6 = *(const uint2*)(xwsh + (long long)s6 * 64 + 4 * fl);
            uint2 u7 = *(const uint2*)(xwsh + (long long)s7 * 64 + 4 * fl);
            float2 f0a = __half22float2(*(const __half2*)&u0.x);
            float2 f0b = __half22float2(*(const __half2*)&u0.y);
            float2 f1a = __half22float2(*(const __half2*)&u1.x);
            float2 f1b = __half22float2(*(const __half2*)&u1.y);
            float2 f2a = __half22float2(*(const __half2*)&u2.x);
            float2 f2b = __half22float2(*(const __half2*)&u2.y);
            float2 f3a = __half22float2(*(const __half2*)&u3.x);
            float2 f3b = __half22float2(*(const __half2*)&u3.y);
            float2 f4a = __half22float2(*(const __half2*)&u4.x);
            float2 f4b = __half22float2(*(const __half2*)&u4.y);
            float2 f5a = __half22float2(*(const __half2*)&u5.x);
            float2 f5b = __half22float2(*(const __half2*)&u5.y);
            float2 f6a = __half22float2(*(const __half2*)&u6.x);
            float2 f6b = __half22float2(*(const __half2*)&u6.y);
            float2 f7a = __half22float2(*(const __half2*)&u7.x);
            float2 f7b = __half22float2(*(const __half2*)&u7.y);
            ax += ((f0a.x + f1a.x) + (f2a.x + f3a.x)) +
                  ((f4a.x + f5a.x) + (f6a.x + f7a.x));
            ay += ((f0a.y + f1a.y) + (f2a.y + f3a.y)) +
                  ((f4a.y + f5a.y) + (f6a.y + f7a.y));
            az += ((f0b.x + f1b.x) + (f2b.x + f3b.x)) +
                  ((f4b.x + f5b.x) + (f6b.x + f7b.x));
            aw += ((f0b.y + f1b.y) + (f2b.y + f3b.y)) +
                  ((f4b.y + f5b.y) + (f6b.y + f7b.y));
        }
        for (; j + 3 < n; j += 4) {
            int s0 = lcsr[jb + j],     s1 = lcsr[jb + j + 1];
            int s2 = lcsr[jb + j + 2], s3 = lcsr[jb + j + 3];
            uint2 u0 = *(const uint2*)(xwsh + (long long)s0 * 64 + 4 * fl);
            uint2 u1 = *(const uint2*)(xwsh + (long long)s1 * 64 + 4 * fl);
            uint2 u2 = *(const uint2*)(xwsh + (long long)s2 * 64 + 4 * fl);
            uint2 u3 = *(const uint2*)(xwsh + (long long)s3 * 64 + 4 * fl);
            float2 f0a = __half22float2(*(const __half2*)&u0.x);
            float2 f0b = __half22float2(*(const __half2*)&u0.y);
            float2 f1a = __half22float2(*(const __half2*)&u1.x);
            float2 f1b = __half22float2(*(const __half2*)&u1.y);
            float2 f2a = __half22float2(*(const __half2*)&u2.x);
            float2 f2b = __half22float2(*(const __half2*)&u2.y);
            float2 f3a = __half22float2(*(const __half2*)&u3.x);
            float2 f3b = __half22float2(*(const __half2*)&u3.y);
            ax += (f0a.x + f1a.x) + (f2a.x + f3a.x);
            ay += (f0a.y + f1a.y) + (f2a.y + f3a.y);
            az += (f0b.x + f1b.x) + (f2b.x + f3b.x);
            aw += (f0b.y + f1b.y) + (f2b.y + f3b.y);
        }
        for (; j < n; ++j) {
            int s = lcsr[jb + j];
            uint2 u = *(const uint2*)(xwsh + (long long)s * 64 + 4 * fl);
            float2 f01 = __half22float2(*(const __half2*)&u.x);
            float2 f23 = __half22float2(*(const __half2*)&u.y);
            ax += f01.x; ay += f01.y; az += f23.x; aw += f23.y;
        }
        uint2 u = *(const uint2*)(xwsh + (long long)d * 64 + 4 * fl);  // self
        float2 s01 = __half22float2(*(const __half2*)&u.x);
        float2 s23 = __half22float2(*(const __half2*)&u.y);
        float di = rsqrtf((float)n + 1.0f);
        float4 v;
        v.x = di * (ax + s01.x) + b4.x;
        v.y = di * (ay + s01.y) + b4.y;
        v.z = di * (az + s23.x) + b4.z;
        v.w = di * (aw + s23.y) + b4.w;
        v.x = v.x >= 0.f ? v.x : slope * v.x;
        v.y = v.y >= 0.f ? v.y : slope * v.y;
        v.z = v.z >= 0.f ? v.z : slope * v.z;
        v.w = v.w >= 0.f ? v.w : slope * v.w;
        *(float4*)(out + (long long)d * 64 + 4 * fl) = v;
    }
}

extern "C" void kernel_launch(void* const* d_in, const int* in_sizes, int n_in,
                              void* d_out, int out_size, void* d_ws, size_t ws_size,
                              hipStream_t stream) {
    const float* x  = (const float*)d_in[0];
    const int*   ei = (const int*)d_in[1];
    const float* W  = (const float*)d_in[2];
    const float* b  = (const float*)d_in[3];
    const float* pa = (const float*)d_in[4];
    float* out = (float*)d_out;

    const int N = in_sizes[0] / 64;
    const long long E = (long long)in_sizes[1] / 2;
    const int nbuk = (N + 127) >> 7;           // 782 for N=100k (<= NBUK_MAX)
    int nscat = iceil(E, SCTH * BUFK);
    if (nscat < 256) nscat = 256;              // keep all CUs busy
    const int chunk = iceil(E, nscat);

    char* ws = (char*)d_ws;
    size_t o = 0;
    int*    flag  = (int*)(ws + o);   o += 256;
    int*    gcur  = (int*)(ws + o);   o += ((size_t)nbuk * 4 + 255) & ~(size_t)255;
    int2*   meta  = (int2*)(ws + o);  o += ((size_t)N * 8 + 255) & ~(size_t)255;
    int*    part  = (int*)(ws + o);   o += ((size_t)nbuk * CAP * 4 + 255) & ~(size_t)255;
    __half* xwsh  = (__half*)(ws + o);  // N*64*2 = 12.8 MB; total ~27 MB

    k_detect<<<1, 256, 0, stream>>>(ei, (long long)in_sizes[1], flag, gcur, nbuk);
    k_scat<<<nscat, SCTH, 0, stream>>>(ei, flag, gcur, part, E, nbuk, chunk);
    k_gemmmeta<<<nbuk, 256, 0, stream>>>(part, gcur, x, W, meta, xwsh, N);
    k_gfuse<<<nbuk, 512, 0, stream>>>(part, gcur, meta, xwsh, b, pa, out, N);
}

// Round 19
// 80.204 us; speedup vs baseline: 2.1369x; 1.0814x over previous
//
#include <hip/hip_runtime.h>
#include <hip/hip_fp16.h>

// GCNConv (self-loops, symmetric norm) + bias + PReLU, fp32, N=100k, D=64, E=1.6M.
//
// Padded-bucket front end; MFMA-f16 gemm with fused meta; fused LDS-CSR gather:
//   0. memset:     gcur[nbuk] = 0 (bucket fill counters)
//   1. k_scat:     per-wave inline layout-detect; single-read register-buffered
//                  pass; LDS count -> one global atomicAdd per (block,bucket)
//                  -> LDS-rank write of (dst&127)<<17|src into padded part[]
//   2. k_gemmmeta: block bb = bucket bb = row tile bb (128 rows). Counts its
//                  part segment + scan -> meta[d]=(cnt,exc), dinv in LDS; then
//                  xwsh = fp16((x @ W) * dinv[row]) via mfma_f32_16x16x32_f16.
//   3. k_gfuse:    per-bucket: rank-place csr in LDS using meta, then 8-deep
//                  unrolled gather from LDS indices; fused epilogue.

static inline int iceil(long long a, int b) { return (int)((a + (long long)b - 1) / b); }

#define CAP 4096          // padded slots per 128-dst bucket (mean fill ~2046)
#define NBUK_MAX 1024     // supports N <= 131072
#define SCTH 1024         // scatter block threads
#define BUFK 8            // edges buffered per thread (chunk <= SCTH*BUFK)

typedef __attribute__((ext_vector_type(8))) _Float16 half8;
typedef __attribute__((ext_vector_type(4))) float floatx4;

// single-READ scatter with inline layout detect: buffer <=BUFK edges in
// registers, LDS count, one global reserve atomic per nonempty (block,bucket),
// LDS-rank place from registers.
__global__ __launch_bounds__(SCTH) void k_scat(const int* __restrict__ ei,
                                               int* __restrict__ gcur,
                                               int* __restrict__ part,
                                               long long E, int nbuk, int chunk,
                                               long long n_i32) {
    __shared__ int hist[NBUK_MAX];
    __shared__ int sbase[NBUK_MAX];
    const int t = threadIdx.x;
    // per-wave layout detect: sample 64 odd int32 slots spread over the array.
    // int64 (values < 2^31) -> all high words zero -> stride st=2; else st=1.
    long long half = n_i32 >> 1;
    long long step = half >> 6;
    if (step == 0) step = 1;
    long long sk = (long long)(t & 63) * step;
    int sample = (sk < half) ? ei[2 * sk + 1] : 0;
    const int st = __any(sample != 0) ? 1 : 2;

    for (int i = t; i < nbuk; i += SCTH) hist[i] = 0;
    __syncthreads();
    const long long beg = (long long)blockIdx.x * chunk;
    long long end = beg + chunk; if (end > E) end = E;

    int bs[BUFK], bd[BUFK];
#pragma unroll
    for (int kk = 0; kk < BUFK; ++kk) {
        long long e = beg + t + (long long)kk * SCTH;
        bool v = e < end;
        bs[kk] = v ? ei[e * st] : 0;
        bd[kk] = v ? ei[(E + e) * st] : -1;
    }
#pragma unroll
    for (int kk = 0; kk < BUFK; ++kk)
        if (bd[kk] >= 0) atomicAdd(&hist[bd[kk] >> 7], 1);
    __syncthreads();
    for (int i = t; i < nbuk; i += SCTH) {
        int c = hist[i];
        sbase[i] = c ? (i * CAP + atomicAdd(&gcur[i], c)) : 0;
        hist[i] = 0;  // reuse as rank counter
    }
    __syncthreads();
#pragma unroll
    for (int kk = 0; kk < BUFK; ++kk) {
        if (bd[kk] >= 0) {
            int b = bd[kk] >> 7;
            int r = atomicAdd(&hist[b], 1);
            part[sbase[b] + r] = ((bd[kk] & 127) << 17) | bs[kk];  // s < 2^17
        }
    }
}

// fused meta + MFMA gemm: block bb = bucket bb = row tile bb (128 rows).
// Phase A: count part segment per dst + scan -> meta (for gfuse), dinv in LDS.
// Phase B: xwsh = fp16((x @ W) * dinvL[row]) via v_mfma_f32_16x16x32_f16.
//   A-frag: lane holds x[row = lane&15][k = (lane>>4)*8 + i], i<8 (per K-step)
//   B-frag: lane holds W[k = (lane>>4)*8 + i][n = lane&15]; staged transposed
//           f16 in LDS as Wth[n][k] so the frag is one 16B contiguous read.
//   C/D:    col = lane&15, row = (lane>>4)*4 + r  (HW-verified mapping)
__global__ __launch_bounds__(256) void k_gemmmeta(const int* __restrict__ part,
                                                  const int* __restrict__ gcur,
                                                  const float* __restrict__ x,
                                                  const float* __restrict__ W,
                                                  int2* __restrict__ meta,
                                                  __half* __restrict__ xwsh, int N) {
    __shared__ _Float16 Wth[64 * 64];   // [n][k] transposed, 8 KB
    __shared__ int cnt[128], inc[128];
    __shared__ float dinvL[128];
    const int tid = threadIdx.x;
    const int bb = blockIdx.x;
    const int tile0 = bb * 128;

    if (tid < 128) cnt[tid] = 0;
    __syncthreads();

    // stage W transposed as f16 (one-time, 4096 elems)
    {
        const float4* W4 = (const float4*)W;
#pragma unroll
        for (int j = 0; j < 4; ++j) {
            int idx = tid + 256 * j;        // float4 index into 64x64
            float4 v = W4[idx];
            int k = idx >> 4;               // row of W (k dim)
            int n0 = (idx & 15) * 4;        // col base
            Wth[(n0 + 0) * 64 + k] = (_Float16)v.x;
            Wth[(n0 + 1) * 64 + k] = (_Float16)v.y;
            Wth[(n0 + 2) * 64 + k] = (_Float16)v.z;
            Wth[(n0 + 3) * 64 + k] = (_Float16)v.w;
        }
    }
    // count this bucket's part segment
    {
        const int beg = bb * CAP, end = bb * CAP + gcur[bb];
        for (int i = beg + tid; i < end; i += 256)
            atomicAdd(&cnt[(part[i] >> 17) & 127], 1);
    }
    __syncthreads();
    if (tid < 128) inc[tid] = cnt[tid];
    __syncthreads();
    for (int off = 1; off < 128; off <<= 1) {
        int v = (tid < 128 && tid >= off) ? inc[tid - off] : 0;
        __syncthreads();
        if (tid < 128) inc[tid] += v;
        __syncthreads();
    }
    if (tid < 128) {
        dinvL[tid] = rsqrtf((float)cnt[tid] + 1.0f);  // +1 self loop
        int d = tile0 + tid;
        if (d < N) meta[d] = make_int2(cnt[tid], inc[tid] - cnt[tid]);
    }
    __syncthreads();

    const int lane = tid & 63;
    const int w = tid >> 6;          // wave 0..3
    const int mrow = lane & 15;
    const int kq = lane >> 4;        // 0..3

    // B fragments: 4 col-tiles x 2 K-steps, each one 16B LDS read
    half8 bf[4][2];
#pragma unroll
    for (int ct = 0; ct < 4; ++ct)
#pragma unroll
        for (int ks = 0; ks < 2; ++ks)
            bf[ct][ks] = *(const half8*)&Wth[(ct * 16 + mrow) * 64 + ks * 32 + kq * 8];

#pragma unroll
    for (int p = 0; p < 2; ++p) {
        const int rt = w * 2 + p;               // row tile 0..7
        int gr = tile0 + rt * 16 + mrow;
        if (gr >= N) gr = N - 1;                // clamp (stores guarded)
        const float* xr = x + (long long)gr * 64 + kq * 8;
        float4 u0 = *(const float4*)xr;
        float4 u1 = *(const float4*)(xr + 4);
        float4 u2 = *(const float4*)(xr + 32);
        float4 u3 = *(const float4*)(xr + 36);
        half8 a0, a1;
        a0[0] = (_Float16)u0.x; a0[1] = (_Float16)u0.y;
        a0[2] = (_Float16)u0.z; a0[3] = (_Float16)u0.w;
        a0[4] = (_Float16)u1.x; a0[5] = (_Float16)u1.y;
        a0[6] = (_Float16)u1.z; a0[7] = (_Float16)u1.w;
        a1[0] = (_Float16)u2.x; a1[1] = (_Float16)u2.y;
        a1[2] = (_Float16)u2.z; a1[3] = (_Float16)u2.w;
        a1[4] = (_Float16)u3.x; a1[5] = (_Float16)u3.y;
        a1[6] = (_Float16)u3.z; a1[7] = (_Float16)u3.w;
#pragma unroll
        for (int ct = 0; ct < 4; ++ct) {
            floatx4 acc = {0.f, 0.f, 0.f, 0.f};
            acc = __builtin_amdgcn_mfma_f32_16x16x32_f16(a0, bf[ct][0], acc, 0, 0, 0);
            acc = __builtin_amdgcn_mfma_f32_16x16x32_f16(a1, bf[ct][1], acc, 0, 0, 0);
#pragma unroll
            for (int r = 0; r < 4; ++r) {
                int m = rt * 16 + kq * 4 + r;   // C/D row
                int d = tile0 + m;
                if (d < N)
                    xwsh[(long long)d * 64 + ct * 16 + mrow] =
                        __float2half(acc[r] * dinvL[m]);
            }
        }
    }
}

// fused bucket kernel: rank-place csr in LDS (counts/offsets from meta), then
// gather. 16-lane group owns one dst at a time (4 features/lane), 8-deep
// unrolled row loads (32 rows in flight per wave).
__global__ __launch_bounds__(512) void k_gfuse(const int* __restrict__ part,
                                               const int* __restrict__ gcur,
                                               const int2* __restrict__ meta,
                                               const __half* __restrict__ xwsh,
                                               const float* __restrict__ b,
                                               const float* __restrict__ pa,
                                               float* __restrict__ out, int N) {
    __shared__ int cnt[128], exc[128], rnk[128];
    __shared__ int lcsr[CAP];
    const int t = threadIdx.x;
    const int bb = blockIdx.x;
    const int beg = bb * CAP, end = bb * CAP + gcur[bb];
    const int tile0 = bb * 128;
    if (t < 128) {
        int d = tile0 + t;
        int2 m = (d < N) ? meta[d] : make_int2(0, 0);
        cnt[t] = m.x;
        exc[t] = m.y;
        rnk[t] = 0;
    }
    __syncthreads();
    for (int i = beg + t; i < end; i += 512) {
        int v = part[i];
        int dl = (v >> 17) & 127;
        int r = atomicAdd(&rnk[dl], 1);
        lcsr[exc[dl] + r] = v & 0x1FFFF;
    }
    __syncthreads();

    const int lane = t & 63;
    const int g = lane >> 4;        // group 0..3 within wave
    const int fl = lane & 15;       // feature quad
    const int wib = t >> 6;         // wave 0..7
    const int q = wib * 4 + g;      // group 0..31 in block
    const float slope = pa[0];
    const float4 b4 = ((const float4*)b)[fl];

    for (int dl = q; dl < 128; dl += 32) {
        int d = tile0 + dl;
        if (d >= N) break;
        const int jb = exc[dl];
        const int n = cnt[dl];
        float ax = 0.f, ay = 0.f, az = 0.f, aw = 0.f;
        int j = 0;
        for (; j + 7 < n; j += 8) {
            int s0 = lcsr[jb + j],     s1 = lcsr[jb + j + 1];
            int s2 = lcsr[jb + j + 2], s3 = lcsr[jb + j + 3];
            int s4 = lcsr[jb + j + 4], s5 = lcsr[jb + j + 5];
            int s6 = lcsr[jb + j + 6], s7 = lcsr[jb + j + 7];
            uint2 u0 = *(const uint2*)(xwsh + (long long)s0 * 64 + 4 * fl);
            uint2 u1 = *(const uint2*)(xwsh + (long long)s1 * 64 + 4 * fl);
            uint2 u2 = *(const uint2*)(xwsh + (long long)s2 * 64 + 4 * fl);
            uint2 u3 = *(const uint2*)(xwsh + (long long)s3 * 64 + 4 * fl);
            uint2 u4 = *(const uint2*)(xwsh + (long long)s4 * 64 + 4 * fl);
            uint2 u5 = *(const uint2*)(xwsh + (long long)s5 * 64 + 4 * fl);
            uint2 u6 = *(const uint2*)(xwsh + (long long)s6 * 64 + 4 * fl);
            uint2 u7 = *(const uint2*)(xwsh + (long long)s7 * 64 + 4 * fl);
            float2 f0a = __half22float2(*(const __half2*)&u0.x);
            float2 f0b = __half22float2(*(const __half2*)&u0.y);
            float2 f1a = __half22float2(*(const __half2*)&u1.x);
            float2 f1b = __half22float2(*(const __half2*)&u1.y);
            float2 f2a = __half22float2(*(const __half2*)&u2.x);
            float2 f2b = __half22float2(*(const __half2*)&u2.y);
            float2 f3a = __half22float2(*(const __half2*)&u3.x);
            float2 f3b = __half22float2(*(const __half2*)&u3.y);
            float2 f4a = __half22float2(*(const __half2*)&u4.x);
            float2 f4b = __half22float2(*(const __half2*)&u4.y);
            float2 f5a = __half22float2(*(const __half2*)&u5.x);
            float2 f5b = __half22float2(*(const __half2*)&u5.y);
            float2 f6a = __half22float2(*(const __half2*)&u6.x);
            float2 f6b = __half22float2(*(const __half2*)&u6.y);
            float2 f7a = __half22float2(*(const __half2*)&u7.x);
            float2 f7b = __half22float2(*(const __half2*)&u7.y);
            ax += ((f0a.x + f1a.x) + (f2a.x + f3a.x)) +
                  ((f4a.x + f5a.x) + (f6a.x + f7a.x));
            ay += ((f0a.y + f1a.y) + (f2a.y + f3a.y)) +
                  ((f4a.y + f5a.y) + (f6a.y + f7a.y));
            az += ((f0b.x + f1b.x) + (f2b.x + f3b.x)) +
                  ((f4b.x + f5b.x) + (f6b.x + f7b.x));
            aw += ((f0b.y + f1b.y) + (f2b.y + f3b.y)) +
                  ((f4b.y + f5b.y) + (f6b.y + f7b.y));
        }
        for (; j + 3 < n; j += 4) {
            int s0 = lcsr[jb + j],     s1 = lcsr[jb + j + 1];
            int s2 = lcsr[jb + j + 2], s3 = lcsr[jb + j + 3];
            uint2 u0 = *(const uint2*)(xwsh + (long long)s0 * 64 + 4 * fl);
            uint2 u1 = *(const uint2*)(xwsh + (long long)s1 * 64 + 4 * fl);
            uint2 u2 = *(const uint2*)(xwsh + (long long)s2 * 64 + 4 * fl);
            uint2 u3 = *(const uint2*)(xwsh + (long long)s3 * 64 + 4 * fl);
            float2 f0a = __half22float2(*(const __half2*)&u0.x);
            float2 f0b = __half22float2(*(const __half2*)&u0.y);
            float2 f1a = __half22float2(*(const __half2*)&u1.x);
            float2 f1b = __half22float2(*(const __half2*)&u1.y);
            float2 f2a = __half22float2(*(const __half2*)&u2.x);
            float2 f2b = __half22float2(*(const __half2*)&u2.y);
            float2 f3a = __half22float2(*(const __half2*)&u3.x);
            float2 f3b = __half22float2(*(const __half2*)&u3.y);
            ax += (f0a.x + f1a.x) + (f2a.x + f3a.x);
            ay += (f0a.y + f1a.y) + (f2a.y + f3a.y);
            az += (f0b.x + f1b.x) + (f2b.x + f3b.x);
            aw += (f0b.y + f1b.y) + (f2b.y + f3b.y);
        }
        for (; j < n; ++j) {
            int s = lcsr[jb + j];
            uint2 u = *(const uint2*)(xwsh + (long long)s * 64 + 4 * fl);
            float2 f01 = __half22float2(*(const __half2*)&u.x);
            float2 f23 = __half22float2(*(const __half2*)&u.y);
            ax += f01.x; ay += f01.y; az += f23.x; aw += f23.y;
        }
        uint2 u = *(const uint2*)(xwsh + (long long)d * 64 + 4 * fl);  // self
        float2 s01 = __half22float2(*(const __half2*)&u.x);
        float2 s23 = __half22float2(*(const __half2*)&u.y);
        float di = rsqrtf((float)n + 1.0f);
        float4 v;
        v.x = di * (ax + s01.x) + b4.x;
        v.y = di * (ay + s01.y) + b4.y;
        v.z = di * (az + s23.x) + b4.z;
        v.w = di * (aw + s23.y) + b4.w;
        v.x = v.x >= 0.f ? v.x : slope * v.x;
        v.y = v.y >= 0.f ? v.y : slope * v.y;
        v.z = v.z >= 0.f ? v.z : slope * v.z;
        v.w = v.w >= 0.f ? v.w : slope * v.w;
        *(float4*)(out + (long long)d * 64 + 4 * fl) = v;
    }
}

extern "C" void kernel_launch(void* const* d_in, const int* in_sizes, int n_in,
                              void* d_out, int out_size, void* d_ws, size_t ws_size,
                              hipStream_t stream) {
    const float* x  = (const float*)d_in[0];
    const int*   ei = (const int*)d_in[1];
    const float* W  = (const float*)d_in[2];
    const float* b  = (const float*)d_in[3];
    const float* pa = (const float*)d_in[4];
    float* out = (float*)d_out;

    const int N = in_sizes[0] / 64;
    const long long E = (long long)in_sizes[1] / 2;
    const int nbuk = (N + 127) >> 7;           // 782 for N=100k (<= NBUK_MAX)
    int nscat = iceil(E, SCTH * BUFK);
    if (nscat < 256) nscat = 256;              // keep all CUs busy
    const int chunk = iceil(E, nscat);

    char* ws = (char*)d_ws;
    size_t o = 0;
    int*    gcur  = (int*)(ws + o);   o += ((size_t)nbuk * 4 + 255) & ~(size_t)255;
    int2*   meta  = (int2*)(ws + o);  o += ((size_t)N * 8 + 255) & ~(size_t)255;
    int*    part  = (int*)(ws + o);   o += ((size_t)nbuk * CAP * 4 + 255) & ~(size_t)255;
    __half* xwsh  = (__half*)(ws + o);  // N*64*2 = 12.8 MB; total ~27 MB

    hipMemsetAsync(gcur, 0, (size_t)nbuk * 4, stream);
    k_scat<<<nscat, SCTH, 0, stream>>>(ei, gcur, part, E, nbuk, chunk,
                                       (long long)in_sizes[1]);
    k_gemmmeta<<<nbuk, 256, 0, stream>>>(part, gcur, x, W, meta, xwsh, N);
    k_gfuse<<<nbuk, 512, 0, stream>>>(part, gcur, meta, xwsh, b, pa, out, N);
}

// Round 20
// 79.446 us; speedup vs baseline: 2.1573x; 1.0095x over previous
//
#include <hip/hip_runtime.h>
#include <hip/hip_fp16.h>

// GCNConv (self-loops, symmetric norm) + bias + PReLU, fp32, N=100k, D=64, E=1.6M.
//
// Padded-bucket front end; MFMA-f16 gemm with fused meta; half-bucket gather:
//   0. memset:     gcur[nbuk] = 0 (bucket fill counters)
//   1. k_scat:     per-wave inline layout-detect; single-read register-buffered
//                  pass; LDS count -> one global atomicAdd per (block,bucket)
//                  -> LDS-rank write of (dst&127)<<17|src into padded part[]
//   2. k_gemmmeta: block bb = bucket bb = row tile bb (128 rows). Counts its
//                  part segment + scan -> meta[d]=(cnt,exc), dinv in LDS; then
//                  xwsh = fp16((x @ W) * dinv[row]) via mfma_f32_16x16x32_f16.
//   3. k_gfuse:    TWO blocks per bucket (64 dsts each) to kill the grid-tail:
//                  rank-place this half's csr in LDS using meta, then 8-deep
//                  unrolled gather from LDS indices; fused epilogue.

static inline int iceil(long long a, int b) { return (int)((a + (long long)b - 1) / b); }

#define CAP 4096          // padded slots per 128-dst bucket (mean fill ~2046)
#define NBUK_MAX 1024     // supports N <= 131072
#define SCTH 1024         // scatter block threads
#define BUFK 8            // edges buffered per thread (chunk <= SCTH*BUFK)

typedef __attribute__((ext_vector_type(8))) _Float16 half8;
typedef __attribute__((ext_vector_type(4))) float floatx4;

// single-READ scatter with inline layout detect: buffer <=BUFK edges in
// registers, LDS count, one global reserve atomic per nonempty (block,bucket),
// LDS-rank place from registers.
__global__ __launch_bounds__(SCTH) void k_scat(const int* __restrict__ ei,
                                               int* __restrict__ gcur,
                                               int* __restrict__ part,
                                               long long E, int nbuk, int chunk,
                                               long long n_i32) {
    __shared__ int hist[NBUK_MAX];
    __shared__ int sbase[NBUK_MAX];
    const int t = threadIdx.x;
    // per-wave layout detect: sample 64 odd int32 slots spread over the array.
    // int64 (values < 2^31) -> all high words zero -> stride st=2; else st=1.
    long long half = n_i32 >> 1;
    long long step = half >> 6;
    if (step == 0) step = 1;
    long long sk = (long long)(t & 63) * step;
    int sample = (sk < half) ? ei[2 * sk + 1] : 0;
    const int st = __any(sample != 0) ? 1 : 2;

    for (int i = t; i < nbuk; i += SCTH) hist[i] = 0;
    __syncthreads();
    const long long beg = (long long)blockIdx.x * chunk;
    long long end = beg + chunk; if (end > E) end = E;

    int bs[BUFK], bd[BUFK];
#pragma unroll
    for (int kk = 0; kk < BUFK; ++kk) {
        long long e = beg + t + (long long)kk * SCTH;
        bool v = e < end;
        bs[kk] = v ? ei[e * st] : 0;
        bd[kk] = v ? ei[(E + e) * st] : -1;
    }
#pragma unroll
    for (int kk = 0; kk < BUFK; ++kk)
        if (bd[kk] >= 0) atomicAdd(&hist[bd[kk] >> 7], 1);
    __syncthreads();
    for (int i = t; i < nbuk; i += SCTH) {
        int c = hist[i];
        sbase[i] = c ? (i * CAP + atomicAdd(&gcur[i], c)) : 0;
        hist[i] = 0;  // reuse as rank counter
    }
    __syncthreads();
#pragma unroll
    for (int kk = 0; kk < BUFK; ++kk) {
        if (bd[kk] >= 0) {
            int b = bd[kk] >> 7;
            int r = atomicAdd(&hist[b], 1);
            part[sbase[b] + r] = ((bd[kk] & 127) << 17) | bs[kk];  // s < 2^17
        }
    }
}

// fused meta + MFMA gemm: block bb = bucket bb = row tile bb (128 rows).
// Phase A: count part segment per dst + scan -> meta (for gfuse), dinv in LDS.
// Phase B: xwsh = fp16((x @ W) * dinvL[row]) via v_mfma_f32_16x16x32_f16.
__global__ __launch_bounds__(256) void k_gemmmeta(const int* __restrict__ part,
                                                  const int* __restrict__ gcur,
                                                  const float* __restrict__ x,
                                                  const float* __restrict__ W,
                                                  int2* __restrict__ meta,
                                                  __half* __restrict__ xwsh, int N) {
    __shared__ _Float16 Wth[64 * 64];   // [n][k] transposed, 8 KB
    __shared__ int cnt[128], inc[128];
    __shared__ float dinvL[128];
    const int tid = threadIdx.x;
    const int bb = blockIdx.x;
    const int tile0 = bb * 128;

    if (tid < 128) cnt[tid] = 0;
    __syncthreads();

    // stage W transposed as f16 (one-time, 4096 elems)
    {
        const float4* W4 = (const float4*)W;
#pragma unroll
        for (int j = 0; j < 4; ++j) {
            int idx = tid + 256 * j;        // float4 index into 64x64
            float4 v = W4[idx];
            int k = idx >> 4;               // row of W (k dim)
            int n0 = (idx & 15) * 4;        // col base
            Wth[(n0 + 0) * 64 + k] = (_Float16)v.x;
            Wth[(n0 + 1) * 64 + k] = (_Float16)v.y;
            Wth[(n0 + 2) * 64 + k] = (_Float16)v.z;
            Wth[(n0 + 3) * 64 + k] = (_Float16)v.w;
        }
    }
    // count this bucket's part segment
    {
        const int beg = bb * CAP, end = bb * CAP + gcur[bb];
        for (int i = beg + tid; i < end; i += 256)
            atomicAdd(&cnt[(part[i] >> 17) & 127], 1);
    }
    __syncthreads();
    if (tid < 128) inc[tid] = cnt[tid];
    __syncthreads();
    for (int off = 1; off < 128; off <<= 1) {
        int v = (tid < 128 && tid >= off) ? inc[tid - off] : 0;
        __syncthreads();
        if (tid < 128) inc[tid] += v;
        __syncthreads();
    }
    if (tid < 128) {
        dinvL[tid] = rsqrtf((float)cnt[tid] + 1.0f);  // +1 self loop
        int d = tile0 + tid;
        if (d < N) meta[d] = make_int2(cnt[tid], inc[tid] - cnt[tid]);
    }
    __syncthreads();

    const int lane = tid & 63;
    const int w = tid >> 6;          // wave 0..3
    const int mrow = lane & 15;
    const int kq = lane >> 4;        // 0..3

    // B fragments: 4 col-tiles x 2 K-steps, each one 16B LDS read
    half8 bf[4][2];
#pragma unroll
    for (int ct = 0; ct < 4; ++ct)
#pragma unroll
        for (int ks = 0; ks < 2; ++ks)
            bf[ct][ks] = *(const half8*)&Wth[(ct * 16 + mrow) * 64 + ks * 32 + kq * 8];

#pragma unroll
    for (int p = 0; p < 2; ++p) {
        const int rt = w * 2 + p;               // row tile 0..7
        int gr = tile0 + rt * 16 + mrow;
        if (gr >= N) gr = N - 1;                // clamp (stores guarded)
        const float* xr = x + (long long)gr * 64 + kq * 8;
        float4 u0 = *(const float4*)xr;
        float4 u1 = *(const float4*)(xr + 4);
        float4 u2 = *(const float4*)(xr + 32);
        float4 u3 = *(const float4*)(xr + 36);
        half8 a0, a1;
        a0[0] = (_Float16)u0.x; a0[1] = (_Float16)u0.y;
        a0[2] = (_Float16)u0.z; a0[3] = (_Float16)u0.w;
        a0[4] = (_Float16)u1.x; a0[5] = (_Float16)u1.y;
        a0[6] = (_Float16)u1.z; a0[7] = (_Float16)u1.w;
        a1[0] = (_Float16)u2.x; a1[1] = (_Float16)u2.y;
        a1[2] = (_Float16)u2.z; a1[3] = (_Float16)u2.w;
        a1[4] = (_Float16)u3.x; a1[5] = (_Float16)u3.y;
        a1[6] = (_Float16)u3.z; a1[7] = (_Float16)u3.w;
#pragma unroll
        for (int ct = 0; ct < 4; ++ct) {
            floatx4 acc = {0.f, 0.f, 0.f, 0.f};
            acc = __builtin_amdgcn_mfma_f32_16x16x32_f16(a0, bf[ct][0], acc, 0, 0, 0);
            acc = __builtin_amdgcn_mfma_f32_16x16x32_f16(a1, bf[ct][1], acc, 0, 0, 0);
#pragma unroll
            for (int r = 0; r < 4; ++r) {
                int m = rt * 16 + kq * 4 + r;   // C/D row
                int d = tile0 + m;
                if (d < N)
                    xwsh[(long long)d * 64 + ct * 16 + mrow] =
                        __float2half(acc[r] * dinvL[m]);
            }
        }
    }
}

// half-bucket gather: block = (bucket bb, half h). Rank-place this half's 64
// dsts into LDS csr (offsets from meta, rebased), then gather: 16-lane group
// owns one dst at a time (4 features/lane), 8-deep unrolled row loads.
__global__ __launch_bounds__(256) void k_gfuse(const int* __restrict__ part,
                                               const int* __restrict__ gcur,
                                               const int2* __restrict__ meta,
                                               const __half* __restrict__ xwsh,
                                               const float* __restrict__ b,
                                               const float* __restrict__ pa,
                                               float* __restrict__ out, int N) {
    __shared__ int cnt[64], excL[64], rnk[64];
    __shared__ int lcsr[CAP / 2];
    const int t = threadIdx.x;
    const int bb = blockIdx.x >> 1;
    const int h = blockIdx.x & 1;
    const int tile0 = bb * 128;
    const int d0 = tile0 + h * 64;
    if (d0 >= N) return;
    const int beg = bb * CAP, end = bb * CAP + gcur[bb];
    const int excb = meta[d0].y;   // broadcast load (same addr all lanes)
    if (t < 64) {
        int d = d0 + t;
        int2 m = (d < N) ? meta[d] : make_int2(0, 0);
        cnt[t] = m.x;
        excL[t] = m.y - excb;      // invalid dsts: never referenced (cnt=0)
        rnk[t] = 0;
    }
    __syncthreads();
    for (int i = beg + t; i < end; i += 256) {
        int v = part[i];
        int dl = (v >> 17) & 127;
        if ((dl >> 6) == h) {
            int l = dl & 63;
            int r = atomicAdd(&rnk[l], 1);
            lcsr[excL[l] + r] = v & 0x1FFFF;
        }
    }
    __syncthreads();

    const int lane = t & 63;
    const int g = lane >> 4;        // group 0..3 within wave
    const int fl = lane & 15;       // feature quad
    const int wib = t >> 6;         // wave 0..3
    const int q = wib * 4 + g;      // group 0..15 in block
    const float slope = pa[0];
    const float4 b4 = ((const float4*)b)[fl];

    for (int dl = q; dl < 64; dl += 16) {
        int d = d0 + dl;
        if (d >= N) break;
        const int jb = excL[dl];
        const int n = cnt[dl];
        float ax = 0.f, ay = 0.f, az = 0.f, aw = 0.f;
        int j = 0;
        for (; j + 7 < n; j += 8) {
            int s0 = lcsr[jb + j],     s1 = lcsr[jb + j + 1];
            int s2 = lcsr[jb + j + 2], s3 = lcsr[jb + j + 3];
            int s4 = lcsr[jb + j + 4], s5 = lcsr[jb + j + 5];
            int s6 = lcsr[jb + j + 6], s7 = lcsr[jb + j + 7];
            uint2 u0 = *(const uint2*)(xwsh + (long long)s0 * 64 + 4 * fl);
            uint2 u1 = *(const uint2*)(xwsh + (long long)s1 * 64 + 4 * fl);
            uint2 u2 = *(const uint2*)(xwsh + (long long)s2 * 64 + 4 * fl);
            uint2 u3 = *(const uint2*)(xwsh + (long long)s3 * 64 + 4 * fl);
            uint2 u4 = *(const uint2*)(xwsh + (long long)s4 * 64 + 4 * fl);
            uint2 u5 = *(const uint2*)(xwsh + (long long)s5 * 64 + 4 * fl);
            uint2 u6 = *(const uint2*)(xwsh + (long long)s6 * 64 + 4 * fl);
            uint2 u7 = *(const uint2*)(xwsh + (long long)s7 * 64 + 4 * fl);
            float2 f0a = __half22float2(*(const __half2*)&u0.x);
            float2 f0b = __half22float2(*(const __half2*)&u0.y);
            float2 f1a = __half22float2(*(const __half2*)&u1.x);
            float2 f1b = __half22float2(*(const __half2*)&u1.y);
            float2 f2a = __half22float2(*(const __half2*)&u2.x);
            float2 f2b = __half22float2(*(const __half2*)&u2.y);
            float2 f3a = __half22float2(*(const __half2*)&u3.x);
            float2 f3b = __half22float2(*(const __half2*)&u3.y);
            float2 f4a = __half22float2(*(const __half2*)&u4.x);
            float2 f4b = __half22float2(*(const __half2*)&u4.y);
            float2 f5a = __half22float2(*(const __half2*)&u5.x);
            float2 f5b = __half22float2(*(const __half2*)&u5.y);
            float2 f6a = __half22float2(*(const __half2*)&u6.x);
            float2 f6b = __half22float2(*(const __half2*)&u6.y);
            float2 f7a = __half22float2(*(const __half2*)&u7.x);
            float2 f7b = __half22float2(*(const __half2*)&u7.y);
            ax += ((f0a.x + f1a.x) + (f2a.x + f3a.x)) +
                  ((f4a.x + f5a.x) + (f6a.x + f7a.x));
            ay += ((f0a.y + f1a.y) + (f2a.y + f3a.y)) +
                  ((f4a.y + f5a.y) + (f6a.y + f7a.y));
            az += ((f0b.x + f1b.x) + (f2b.x + f3b.x)) +
                  ((f4b.x + f5b.x) + (f6b.x + f7b.x));
            aw += ((f0b.y + f1b.y) + (f2b.y + f3b.y)) +
                  ((f4b.y + f5b.y) + (f6b.y + f7b.y));
        }
        for (; j + 3 < n; j += 4) {
            int s0 = lcsr[jb + j],     s1 = lcsr[jb + j + 1];
            int s2 = lcsr[jb + j + 2], s3 = lcsr[jb + j + 3];
            uint2 u0 = *(const uint2*)(xwsh + (long long)s0 * 64 + 4 * fl);
            uint2 u1 = *(const uint2*)(xwsh + (long long)s1 * 64 + 4 * fl);
            uint2 u2 = *(const uint2*)(xwsh + (long long)s2 * 64 + 4 * fl);
            uint2 u3 = *(const uint2*)(xwsh + (long long)s3 * 64 + 4 * fl);
            float2 f0a = __half22float2(*(const __half2*)&u0.x);
            float2 f0b = __half22float2(*(const __half2*)&u0.y);
            float2 f1a = __half22float2(*(const __half2*)&u1.x);
            float2 f1b = __half22float2(*(const __half2*)&u1.y);
            float2 f2a = __half22float2(*(const __half2*)&u2.x);
            float2 f2b = __half22float2(*(const __half2*)&u2.y);
            float2 f3a = __half22float2(*(const __half2*)&u3.x);
            float2 f3b = __half22float2(*(const __half2*)&u3.y);
            ax += (f0a.x + f1a.x) + (f2a.x + f3a.x);
            ay += (f0a.y + f1a.y) + (f2a.y + f3a.y);
            az += (f0b.x + f1b.x) + (f2b.x + f3b.x);
            aw += (f0b.y + f1b.y) + (f2b.y + f3b.y);
        }
        for (; j < n; ++j) {
            int s = lcsr[jb + j];
            uint2 u = *(const uint2*)(xwsh + (long long)s * 64 + 4 * fl);
            float2 f01 = __half22float2(*(const __half2*)&u.x);
            float2 f23 = __half22float2(*(const __half2*)&u.y);
            ax += f01.x; ay += f01.y; az += f23.x; aw += f23.y;
        }
        uint2 u = *(const uint2*)(xwsh + (long long)d * 64 + 4 * fl);  // self
        float2 s01 = __half22float2(*(const __half2*)&u.x);
        float2 s23 = __half22float2(*(const __half2*)&u.y);
        float di = rsqrtf((float)n + 1.0f);
        float4 v;
        v.x = di * (ax + s01.x) + b4.x;
        v.y = di * (ay + s01.y) + b4.y;
        v.z = di * (az + s23.x) + b4.z;
        v.w = di * (aw + s23.y) + b4.w;
        v.x = v.x >= 0.f ? v.x : slope * v.x;
        v.y = v.y >= 0.f ? v.y : slope * v.y;
        v.z = v.z >= 0.f ? v.z : slope * v.z;
        v.w = v.w >= 0.f ? v.w : slope * v.w;
        *(float4*)(out + (long long)d * 64 + 4 * fl) = v;
    }
}

extern "C" void kernel_launch(void* const* d_in, const int* in_sizes, int n_in,
                              void* d_out, int out_size, void* d_ws, size_t ws_size,
                              hipStream_t stream) {
    const float* x  = (const float*)d_in[0];
    const int*   ei = (const int*)d_in[1];
    const float* W  = (const float*)d_in[2];
    const float* b  = (const float*)d_in[3];
    const float* pa = (const float*)d_in[4];
    float* out = (float*)d_out;

    const int N = in_sizes[0] / 64;
    const long long E = (long long)in_sizes[1] / 2;
    const int nbuk = (N + 127) >> 7;           // 782 for N=100k (<= NBUK_MAX)
    int nscat = iceil(E, SCTH * BUFK);
    if (nscat < 256) nscat = 256;              // keep all CUs busy
    const int chunk = iceil(E, nscat);

    char* ws = (char*)d_ws;
    size_t o = 0;
    int*    gcur  = (int*)(ws + o);   o += ((size_t)nbuk * 4 + 255) & ~(size_t)255;
    int2*   meta  = (int2*)(ws + o);  o += ((size_t)N * 8 + 255) & ~(size_t)255;
    int*    part  = (int*)(ws + o);   o += ((size_t)nbuk * CAP * 4 + 255) & ~(size_t)255;
    __half* xwsh  = (__half*)(ws + o);  // N*64*2 = 12.8 MB; total ~27 MB

    hipMemsetAsync(gcur, 0, (size_t)nbuk * 4, stream);
    k_scat<<<nscat, SCTH, 0, stream>>>(ei, gcur, part, E, nbuk, chunk,
                                       (long long)in_sizes[1]);
    k_gemmmeta<<<nbuk, 256, 0, stream>>>(part, gcur, x, W, meta, xwsh, N);
    k_gfuse<<<nbuk * 2, 256, 0, stream>>>(part, gcur, meta, xwsh, b, pa, out, N);
}